// Round 7
// baseline (508.525 us; speedup 1.0000x reference)
//
#include <hip/hip_runtime.h>
#include <stdint.h>
#include <stddef.h>

#define N_NODES 100000
#define N_EDGES 1600000
#define F_IN 128
#define EMB 128
#define HEADS 4
#define D_HEAD 32
#define HIDDEN 256
#define BATCH 2048
#define CANDS 16
#define SCAN_B 391    /* ceil(N_NODES/256) */
#define MAXNEED 32768 /* BATCH*CANDS upper bound on unique needed dsts */
#define WXBLOCKS 1563 /* ceil(N_NODES/64) */
#define WTROWS 144    /* 128 W cols + 8 att-projection rows + 8 zero pad */
#define STR 136       /* padded row stride (shorts) */

typedef __attribute__((ext_vector_type(8))) short v8s;
typedef __attribute__((ext_vector_type(4))) float v4f;

__device__ __forceinline__ unsigned short f2bs(float f) {
  unsigned int u = __builtin_bit_cast(unsigned int, f);
  u = (u + 0x7fffu + ((u >> 16) & 1u)) >> 16;
  return (unsigned short)u;
}
__device__ __forceinline__ float bs2f(unsigned int s) {
  unsigned int u = (s & 0xffffu) << 16;
  return __builtin_bit_cast(float, u);
}

// ---------------- prep: padded Wt^T (+att-projection rows) + mark needed -------
__global__ __launch_bounds__(256) void k_prep(const float* __restrict__ W,
                                              const float* __restrict__ att_src,
                                              const float* __restrict__ att_dst,
                                              unsigned short* __restrict__ Wtp,
                                              const int* __restrict__ idx,
                                              unsigned char* __restrict__ needed) {
  int i = blockIdx.x * 256 + threadIdx.x;
  if (i < 128 * STR) {
    int r = i / STR, c = i - r * STR;
    Wtp[i] = (c < 128) ? f2bs(W[c * 128 + r]) : (unsigned short)0;
  } else if (i < WTROWS * STR) {
    int ii = i - 128 * STR;
    int r = ii / STR, c = ii - r * STR;  // r: 0..15
    unsigned short v = 0;
    if (c < 128 && r < 8) {
      const float* att = (r < 4) ? att_src : att_dst;
      int hh = r & 3;
      float s = 0.f;
#pragma unroll
      for (int d = 0; d < 32; ++d) s += W[c * 128 + hh * 32 + d] * att[hh * 32 + d];
      v = f2bs(s);
    }
    Wtp[i] = v;
  }
  if (i < BATCH * CANDS) needed[idx[i]] = 1;
}

// ---------------- Wx = x @ W (MFMA), Wt staged in LDS, a_s/a_d via MFMA --------
__global__ __launch_bounds__(256) void k_wx(const float* __restrict__ x,
                                            const unsigned short* __restrict__ Wtp,
                                            unsigned short* __restrict__ Wx,
                                            float* __restrict__ a_s,
                                            float* __restrict__ a_d) {
  __shared__ unsigned short wt[WTROWS * STR];  // 39168 B
  __shared__ unsigned short xs[64 * STR];      // 17408 B
  int tid = threadIdx.x;
  int rbase = blockIdx.x * 64;

  {
    const uint4* s = (const uint4*)Wtp;
    uint4* d = (uint4*)wt;
#pragma unroll
    for (int it = 0; it < 10; ++it) {
      int i = it * 256 + tid;
      if (i < WTROWS * STR / 8) d[i] = s[i];
    }
  }

  float4 f[8];
#pragma unroll
  for (int it = 0; it < 4; ++it) {
    int cid = it * 256 + tid;
    int row = cid >> 4, c = cid & 15;
    int gr = rbase + row;
    if (gr >= N_NODES) gr = N_NODES - 1;
    const float4* gp = (const float4*)(x + (size_t)gr * 128 + c * 8);
    f[2 * it] = gp[0];
    f[2 * it + 1] = gp[1];
  }
#pragma unroll
  for (int it = 0; it < 4; ++it) {
    int cid = it * 256 + tid;
    int row = cid >> 4, c = cid & 15;
    float4 f0 = f[2 * it], f1 = f[2 * it + 1];
    v8s a;
    a[0] = (short)f2bs(f0.x); a[1] = (short)f2bs(f0.y);
    a[2] = (short)f2bs(f0.z); a[3] = (short)f2bs(f0.w);
    a[4] = (short)f2bs(f1.x); a[5] = (short)f2bs(f1.y);
    a[6] = (short)f2bs(f1.z); a[7] = (short)f2bs(f1.w);
    *(v8s*)(&xs[row * STR + c * 8]) = a;
  }
  __syncthreads();

  int w = tid >> 6, lane = tid & 63;
  int m = lane & 15, quad = lane >> 4;

  v8s afrag[4];
#pragma unroll
  for (int t = 0; t < 4; ++t)
    afrag[t] = *(const v8s*)(&xs[(w * 16 + m) * STR + t * 32 + quad * 8]);

  v4f acc[9];
#pragma unroll
  for (int nt = 0; nt < 9; ++nt) {
    v4f a0 = {0.f, 0.f, 0.f, 0.f};
    const unsigned short* brow = wt + (size_t)(nt * 16 + m) * STR;
#pragma unroll
    for (int t = 0; t < 4; ++t) {
      v8s b = *(const v8s*)(brow + t * 32 + quad * 8);
      a0 = __builtin_amdgcn_mfma_f32_16x16x32_bf16(afrag[t], b, a0, 0, 0, 0);
    }
    acc[nt] = a0;
  }

#pragma unroll
  for (int r = 0; r < 4; ++r) {
    int orow = rbase + w * 16 + quad * 4 + r;
    if (orow < N_NODES) {
      if (m < 4) a_s[(size_t)orow * 4 + m] = acc[8][r];
      else if (m < 8) a_d[(size_t)orow * 4 + m - 4] = acc[8][r];
    }
  }

  __syncthreads();
#pragma unroll
  for (int nt = 0; nt < 8; ++nt)
#pragma unroll
    for (int r = 0; r < 4; ++r)
      xs[(w * 16 + quad * 4 + r) * STR + nt * 16 + m] = f2bs(acc[nt][r]);
  asm volatile("s_waitcnt lgkmcnt(0)" ::: "memory");
#pragma unroll
  for (int j = 0; j < 4; ++j) {
    int fr = 4 * j + (lane >> 4);
    int fc = (lane & 15) * 8;
    int grow = rbase + w * 16 + fr;
    v8s v = *(const v8s*)(&xs[(w * 16 + fr) * STR + fc]);
    if (grow < N_NODES) *(v8s*)(&Wx[(size_t)grow * 128 + fc]) = v;
  }
}

// ---------------- degree count + compacted (src,dst) edge list ----------------
// Wave-aggregated append: one atomicAdd per wave, coalesced int2 writes.
// Replaces k_scatter's 12.8MB ei re-read with a 3.6MB filtered list.
__global__ __launch_bounds__(256) void k_deg(const int* __restrict__ ei,
                                             const unsigned char* __restrict__ needed,
                                             int* __restrict__ deg,
                                             int2* __restrict__ elist,
                                             int* __restrict__ ecnt) {
  int e = blockIdx.x * 256 + threadIdx.x;  // grid exactly covers N_EDGES
  int dst = ei[N_EDGES + e];
  bool act = needed[dst] != 0;
  int src = 0;
  if (act) {
    src = ei[e];
    atomicAdd(&deg[dst], 1);
  }
  unsigned long long mask = __ballot(act);
  int lane = threadIdx.x & 63;
  int pre = __popcll(mask & ((1ull << lane) - 1ull));
  int cnt = __popcll(mask);
  int leader = __ffsll((unsigned long long)mask) - 1;
  int base = 0;
  if (cnt) {
    if (lane == leader) base = atomicAdd(ecnt, cnt);
    base = __shfl(base, leader);
    if (act) elist[base + pre] = make_int2(src, dst);
  }
}

// ---------------- two-level scan ----------------
__global__ __launch_bounds__(256) void k_scan1(const int* __restrict__ deg,
                                               int* __restrict__ row_start,
                                               int* __restrict__ bsum) {
  __shared__ int s[256];
  int tid = threadIdx.x;
  int i = blockIdx.x * 256 + tid;
  int v = (i < N_NODES) ? deg[i] : 0;
  s[tid] = v;
  __syncthreads();
#pragma unroll
  for (int off = 1; off < 256; off <<= 1) {
    int t = 0;
    if (tid >= off) t = s[tid - off];
    __syncthreads();
    s[tid] += t;
    __syncthreads();
  }
  if (i < N_NODES) row_start[i] = s[tid] - v;
  if (tid == 255) bsum[blockIdx.x] = s[255];
}

__global__ __launch_bounds__(512) void k_scan2(int* __restrict__ bsum,
                                               int* __restrict__ row_start) {
  __shared__ int s[512];
  int tid = threadIdx.x;
  int v = (tid < SCAN_B) ? bsum[tid] : 0;
  s[tid] = v;
  __syncthreads();
#pragma unroll
  for (int off = 1; off < 512; off <<= 1) {
    int t = 0;
    if (tid >= off) t = s[tid - off];
    __syncthreads();
    s[tid] += t;
    __syncthreads();
  }
  if (tid < SCAN_B) bsum[tid] = s[tid] - v;
  if (tid == SCAN_B - 1) row_start[N_NODES] = s[tid];
}

__global__ __launch_bounds__(256) void k_scan3(int* __restrict__ row_start,
                                               int* __restrict__ cursor,
                                               const int* __restrict__ bsum,
                                               const unsigned char* __restrict__ needed,
                                               int* __restrict__ nlist,
                                               int* __restrict__ nw_cnt) {
  int i = blockIdx.x * 256 + threadIdx.x;
  if (i >= N_NODES) return;
  int v = row_start[i] + bsum[blockIdx.x];
  row_start[i] = v;
  cursor[i] = v;
  if (needed[i]) {
    int p = atomicAdd(nw_cnt, 1);
    nlist[p] = i;
  }
}

// ---------------- scatter srcs into CSR (4B/edge only; weights recomputed in agg)
__global__ __launch_bounds__(256) void k_scatter(const int2* __restrict__ elist,
                                                 const int* __restrict__ ecnt,
                                                 int* __restrict__ cursor,
                                                 int* __restrict__ srclist) {
  int i = blockIdx.x * 256 + threadIdx.x;
  if (i >= ecnt[0]) return;
  int2 e = elist[i];
  int pos = atomicAdd(&cursor[e.y], 1);
  srclist[pos] = e.x;
}

// ---------------- per-dst aggregation: weights computed in preload ------------
// Lane l gathers a_s[srclist[start+l]] (L2-resident, 1.6MB table) and computes
// w = exp(leaky(a_s+a_d)) for 4 heads; staged to LDS. Inner loop unchanged:
// 2 edges/iter, broadcast ds_reads + one uint2 Wx gather per half-wave.
__global__ __launch_bounds__(256) void k_agg(const float* __restrict__ a_s,
                                             const float* __restrict__ a_d,
                                             const unsigned short* __restrict__ Wx,
                                             const int* __restrict__ nlist,
                                             const int* __restrict__ nw_cnt,
                                             const int* __restrict__ row_start,
                                             const int* __restrict__ srclist,
                                             const float* __restrict__ bias,
                                             unsigned short* __restrict__ hout) {
  __shared__ int sS[4][64];
  __shared__ float sW[4][256];
  int w = threadIdx.x >> 6, lane = threadIdx.x & 63;
  int wid = blockIdx.x * 4 + w;
  int cnt = nw_cnt[0];
  bool act = wid < cnt;
  int dst = 0, start = 0, deg = 0;
  float4 w4 = {0.f, 0.f, 0.f, 0.f};
  float4 ad4 = {0.f, 0.f, 0.f, 0.f};
  if (act) {
    dst = nlist[wid];
    start = row_start[dst];
    deg = row_start[dst + 1] - start;
    ad4 = *(const float4*)(a_d + (size_t)dst * 4);
    if (lane < deg && lane < 64) {
      int sv = srclist[start + lane];
      float4 as = *(const float4*)(a_s + (size_t)sv * 4);
      float e0 = as.x + ad4.x; e0 = e0 > 0.f ? e0 : 0.2f * e0;
      float e1 = as.y + ad4.y; e1 = e1 > 0.f ? e1 : 0.2f * e1;
      float e2 = as.z + ad4.z; e2 = e2 > 0.f ? e2 : 0.2f * e2;
      float e3 = as.w + ad4.w; e3 = e3 > 0.f ? e3 : 0.2f * e3;
      w4.x = __expf(e0); w4.y = __expf(e1);
      w4.z = __expf(e2); w4.w = __expf(e3);
      sS[w][lane] = sv;
      *(float4*)(&sW[w][lane * 4]) = w4;
    }
  }
  __syncthreads();
  if (!act) return;

  int half = lane >> 5, li = lane & 31, hh = li >> 3;
  int nE = deg < 64 ? deg : 64;

  // denominator: preloaded weights (+rare overflow recompute) then butterfly
  float4 denv = w4;
  for (int i = start + 64 + lane; i < start + deg; i += 64) {
    int sv = srclist[i];
    float4 as = *(const float4*)(a_s + (size_t)sv * 4);
    float e0 = as.x + ad4.x; e0 = e0 > 0.f ? e0 : 0.2f * e0;
    float e1 = as.y + ad4.y; e1 = e1 > 0.f ? e1 : 0.2f * e1;
    float e2 = as.z + ad4.z; e2 = e2 > 0.f ? e2 : 0.2f * e2;
    float e3 = as.w + ad4.w; e3 = e3 > 0.f ? e3 : 0.2f * e3;
    denv.x += __expf(e0); denv.y += __expf(e1);
    denv.z += __expf(e2); denv.w += __expf(e3);
  }
#pragma unroll
  for (int o = 32; o >= 1; o >>= 1) {
    denv.x += __shfl_xor(denv.x, o);
    denv.y += __shfl_xor(denv.y, o);
    denv.z += __shfl_xor(denv.z, o);
    denv.w += __shfl_xor(denv.w, o);
  }

  float4 as4 = *(const float4*)(a_s + (size_t)dst * 4);
  float s0 = as4.x + ad4.x; s0 = s0 > 0.f ? s0 : 0.2f * s0;
  float s1 = as4.y + ad4.y; s1 = s1 > 0.f ? s1 : 0.2f * s1;
  float s2 = as4.z + ad4.z; s2 = s2 > 0.f ? s2 : 0.2f * s2;
  float s3 = as4.w + ad4.w; s3 = s3 > 0.f ? s3 : 0.2f * s3;
  float w0 = __expf(s0), w1 = __expf(s1), w2 = __expf(s2), w3 = __expf(s3);
  float wSelf = hh < 2 ? (hh == 0 ? w0 : w1) : (hh == 2 ? w2 : w3);
  float denE = hh < 2 ? (hh == 0 ? denv.x : denv.y) : (hh == 2 ? denv.z : denv.w);
  float den = denE + wSelf;

  float acc0 = 0.f, acc1 = 0.f, acc2 = 0.f, acc3 = 0.f;
  if (half == 0) {
    uint2 u = *(const uint2*)(Wx + (size_t)dst * 128 + li * 4);
    acc0 = wSelf * bs2f(u.x); acc1 = wSelf * bs2f(u.x >> 16);
    acc2 = wSelf * bs2f(u.y); acc3 = wSelf * bs2f(u.y >> 16);
  }

  int j = 0;
#pragma unroll 2
  for (; j + 1 < nE; j += 2) {
    int jj = j + half;
    int s = sS[w][jj];
    float wA = sW[w][jj * 4 + hh];
    uint2 u = *(const uint2*)(Wx + (size_t)s * 128 + li * 4);
    acc0 += wA * bs2f(u.x); acc1 += wA * bs2f(u.x >> 16);
    acc2 += wA * bs2f(u.y); acc3 += wA * bs2f(u.y >> 16);
  }
  if (j < nE && half == 0) {
    int s = sS[w][j];
    float wA = sW[w][j * 4 + hh];
    uint2 u = *(const uint2*)(Wx + (size_t)s * 128 + li * 4);
    acc0 += wA * bs2f(u.x); acc1 += wA * bs2f(u.x >> 16);
    acc2 += wA * bs2f(u.y); acc3 += wA * bs2f(u.y >> 16);
  }
  // overflow tail (deg > 64): recompute weight; effectively never taken
  for (int t = 64; t < deg; ++t) {
    if (half == 0) {
      int s = srclist[start + t];
      float4 as = *(const float4*)(a_s + (size_t)s * 4);
      float ee = (hh == 0 ? as.x + ad4.x : hh == 1 ? as.y + ad4.y
                : hh == 2 ? as.z + ad4.z : as.w + ad4.w);
      ee = ee > 0.f ? ee : 0.2f * ee;
      float wA = __expf(ee);
      uint2 u = *(const uint2*)(Wx + (size_t)s * 128 + li * 4);
      acc0 += wA * bs2f(u.x); acc1 += wA * bs2f(u.x >> 16);
      acc2 += wA * bs2f(u.y); acc3 += wA * bs2f(u.y >> 16);
    }
  }

  acc0 += __shfl_xor(acc0, 32);
  acc1 += __shfl_xor(acc1, 32);
  acc2 += __shfl_xor(acc2, 32);
  acc3 += __shfl_xor(acc3, 32);

  if (half == 0) {
    float inv = 1.0f / den;
    float4 b4 = *(const float4*)(bias + li * 4);
    float r0 = acc0 * inv + b4.x;
    float r1 = acc1 * inv + b4.y;
    float r2 = acc2 * inv + b4.z;
    float r3 = acc3 * inv + b4.w;
    uint2 o;
    o.x = (unsigned int)f2bs(r0) | ((unsigned int)f2bs(r1) << 16);
    o.y = (unsigned int)f2bs(r2) | ((unsigned int)f2bs(r3) << 16);
    *(uint2*)(hout + (size_t)dst * 128 + li * 4) = o;
  }
}

// ---------------- fused: msg = message @ fc_w^T + fc_b, then scoring ----------
__global__ __launch_bounds__(256) void k_msgscore(const float* __restrict__ message,
                                                  const float* __restrict__ fc_w,
                                                  const float* __restrict__ fc_b,
                                                  const unsigned short* __restrict__ h,
                                                  const int* __restrict__ indices,
                                                  float* __restrict__ out) {
  __shared__ float Sm[16][256];
  float* red = &Sm[0][0];
  int tid = threadIdx.x;
  int b0 = blockIdx.x * 16;
  for (int i = tid; i < 16 * 256; i += 256)
    Sm[i >> 8][i & 255] = message[(size_t)b0 * 256 + i];
  __syncthreads();
  int e = tid & 127, half = tid >> 7;
  float acc[16];
#pragma unroll
  for (int r = 0; r < 16; ++r) acc[r] = 0.f;
  const float* wrow = fc_w + (size_t)e * 256 + half * 128;
  for (int k = 0; k < 128; k += 4) {
    float4 w4 = *(const float4*)(wrow + k);
#pragma unroll
    for (int r = 0; r < 16; ++r) {
      float4 m4 = *(const float4*)(&Sm[r][half * 128 + k]);
      acc[r] += m4.x * w4.x + m4.y * w4.y + m4.z * w4.z + m4.w * w4.w;
    }
  }
  __syncthreads();
  if (half == 0) {
#pragma unroll
    for (int r = 0; r < 16; ++r) red[r * 128 + e] = acc[r];
  }
  __syncthreads();
  if (half == 1) {
#pragma unroll
    for (int r = 0; r < 16; ++r) red[r * 128 + e] += acc[r];
  }
  __syncthreads();
  for (int i = tid; i < 2048; i += 256) red[i] += fc_b[i & 127];
  __syncthreads();

  int r = tid >> 4, c = tid & 15;
  int idx = indices[(b0 + r) * 16 + c];
  const unsigned short* hr = h + (size_t)idx * 128;
  const float* mr = red + r * 128;
  float dot = 0.f;
#pragma unroll
  for (int k = 0; k < 128; k += 8) {
    uint4 q = *(const uint4*)(hr + k);
    float4 m0 = *(const float4*)(mr + k);
    float4 m1 = *(const float4*)(mr + k + 4);
    dot += bs2f(q.x) * m0.x + bs2f(q.x >> 16) * m0.y
         + bs2f(q.y) * m0.z + bs2f(q.y >> 16) * m0.w
         + bs2f(q.z) * m1.x + bs2f(q.z >> 16) * m1.y
         + bs2f(q.w) * m1.z + bs2f(q.w >> 16) * m1.w;
  }
  float mx = dot;
#pragma unroll
  for (int o = 1; o < 16; o <<= 1) mx = fmaxf(mx, __shfl_xor(mx, o));
  float ex = __expf(dot - mx);
  float sum = ex;
#pragma unroll
  for (int o = 1; o < 16; o <<= 1) sum += __shfl_xor(sum, o);
  float lse = mx + __logf(sum);
  out[(b0 + r) * 16 + c] = dot - lse;
}

extern "C" void kernel_launch(void* const* d_in, const int* in_sizes, int n_in,
                              void* d_out, int out_size, void* d_ws, size_t ws_size,
                              hipStream_t stream) {
  (void)in_sizes; (void)n_in; (void)out_size; (void)ws_size;
  const float* message = (const float*)d_in[0];
  const float* x       = (const float*)d_in[1];
  const int*   ei      = (const int*)d_in[2];
  const int*   indices = (const int*)d_in[3];
  const float* W       = (const float*)d_in[4];
  const float* att_src = (const float*)d_in[5];
  const float* att_dst = (const float*)d_in[6];
  const float* bias    = (const float*)d_in[7];
  const float* fc_w    = (const float*)d_in[8];
  const float* fc_b    = (const float*)d_in[9];
  float* out = (float*)d_out;

  char* p = (char*)d_ws;
  auto alloc = [&](size_t bytes) -> char* {
    char* r = p;
    p += (bytes + 255) & ~(size_t)255;
    return r;
  };
  unsigned short* Wx = (unsigned short*)alloc((size_t)N_NODES * 128 * 2);
  unsigned short* h  = (unsigned short*)alloc((size_t)N_NODES * 128 * 2);
  float* a_s = (float*)alloc((size_t)N_NODES * 4 * 4);
  float* a_d = (float*)alloc((size_t)N_NODES * 4 * 4);
  unsigned short* Wtp = (unsigned short*)alloc((size_t)WTROWS * STR * 2);
  // ---- zeroed region: needed .. ecnt (one memset) ----
  unsigned char* needed = (unsigned char*)alloc((size_t)N_NODES);
  int* deg       = (int*)alloc((size_t)N_NODES * 4);
  int* nw_cnt    = (int*)alloc(4);
  int* ecnt      = (int*)alloc(4);
  // ---- end zeroed region ----
  int* row_start = (int*)alloc(((size_t)N_NODES + 1) * 4);
  int* cursor    = (int*)alloc((size_t)N_NODES * 4);
  int* bsum      = (int*)alloc((size_t)SCAN_B * 4);
  int* nlist     = (int*)alloc((size_t)MAXNEED * 4);
  int* srclist   = (int*)alloc((size_t)N_EDGES * 4);
  int2* elist    = (int2*)alloc((size_t)N_EDGES * 8);

  hipMemsetAsync(needed, 0, (size_t)((char*)row_start - (char*)needed), stream);

  k_prep<<<128, 256, 0, stream>>>(W, att_src, att_dst, Wtp, indices, needed);
  k_wx<<<WXBLOCKS, 256, 0, stream>>>(x, Wtp, Wx, a_s, a_d);
  k_deg<<<N_EDGES / 256, 256, 0, stream>>>(ei, needed, deg, elist, ecnt);
  k_scan1<<<SCAN_B, 256, 0, stream>>>(deg, row_start, bsum);
  k_scan2<<<1, 512, 0, stream>>>(bsum, row_start);
  k_scan3<<<SCAN_B, 256, 0, stream>>>(row_start, cursor, bsum, needed, nlist, nw_cnt);
  k_scatter<<<N_EDGES / 256, 256, 0, stream>>>(elist, ecnt, cursor, srclist);
  k_agg<<<MAXNEED / 4, 256, 0, stream>>>(a_s, a_d, Wx, nlist, nw_cnt, row_start, srclist, bias, h);
  k_msgscore<<<BATCH / 16, 256, 0, stream>>>(message, fc_w, fc_b, h, indices, out);
}

// Round 8
// 241.422 us; speedup vs baseline: 2.1064x; 2.1064x over previous
//
#include <hip/hip_runtime.h>
#include <stdint.h>
#include <stddef.h>

#define N_NODES 100000
#define N_EDGES 1600000
#define F_IN 128
#define EMB 128
#define HEADS 4
#define D_HEAD 32
#define HIDDEN 256
#define BATCH 2048
#define CANDS 16
#define SCAN_B 391    /* ceil(N_NODES/256) */
#define MAXNEED 32768 /* BATCH*CANDS upper bound on unique needed dsts */
#define WXBLOCKS 1563 /* ceil(N_NODES/64) */
#define WTROWS 144    /* 128 W cols + 8 att-projection rows + 8 zero pad */
#define STR 136       /* padded row stride (shorts) */

typedef __attribute__((ext_vector_type(8))) short v8s;
typedef __attribute__((ext_vector_type(4))) float v4f;

__device__ __forceinline__ unsigned short f2bs(float f) {
  unsigned int u = __builtin_bit_cast(unsigned int, f);
  u = (u + 0x7fffu + ((u >> 16) & 1u)) >> 16;
  return (unsigned short)u;
}
__device__ __forceinline__ float bs2f(unsigned int s) {
  unsigned int u = (s & 0xffffu) << 16;
  return __builtin_bit_cast(float, u);
}

// ---------------- prep: padded Wt^T (+att-projection rows) + mark needed -------
__global__ __launch_bounds__(256) void k_prep(const float* __restrict__ W,
                                              const float* __restrict__ att_src,
                                              const float* __restrict__ att_dst,
                                              unsigned short* __restrict__ Wtp,
                                              const int* __restrict__ idx,
                                              unsigned char* __restrict__ needed) {
  int i = blockIdx.x * 256 + threadIdx.x;
  if (i < 128 * STR) {
    int r = i / STR, c = i - r * STR;
    Wtp[i] = (c < 128) ? f2bs(W[c * 128 + r]) : (unsigned short)0;
  } else if (i < WTROWS * STR) {
    int ii = i - 128 * STR;
    int r = ii / STR, c = ii - r * STR;  // r: 0..15
    unsigned short v = 0;
    if (c < 128 && r < 8) {
      const float* att = (r < 4) ? att_src : att_dst;
      int hh = r & 3;
      float s = 0.f;
#pragma unroll
      for (int d = 0; d < 32; ++d) s += W[c * 128 + hh * 32 + d] * att[hh * 32 + d];
      v = f2bs(s);
    }
    Wtp[i] = v;
  }
  if (i < BATCH * CANDS) needed[idx[i]] = 1;
}

// ---------------- Wx = x @ W (MFMA), Wt staged in LDS, a_s/a_d via MFMA --------
__global__ __launch_bounds__(256) void k_wx(const float* __restrict__ x,
                                            const unsigned short* __restrict__ Wtp,
                                            unsigned short* __restrict__ Wx,
                                            float* __restrict__ a_s,
                                            float* __restrict__ a_d) {
  __shared__ unsigned short wt[WTROWS * STR];  // 39168 B
  __shared__ unsigned short xs[64 * STR];      // 17408 B
  int tid = threadIdx.x;
  int rbase = blockIdx.x * 64;

  {
    const uint4* s = (const uint4*)Wtp;
    uint4* d = (uint4*)wt;
#pragma unroll
    for (int it = 0; it < 10; ++it) {
      int i = it * 256 + tid;
      if (i < WTROWS * STR / 8) d[i] = s[i];
    }
  }

  float4 f[8];
#pragma unroll
  for (int it = 0; it < 4; ++it) {
    int cid = it * 256 + tid;
    int row = cid >> 4, c = cid & 15;
    int gr = rbase + row;
    if (gr >= N_NODES) gr = N_NODES - 1;
    const float4* gp = (const float4*)(x + (size_t)gr * 128 + c * 8);
    f[2 * it] = gp[0];
    f[2 * it + 1] = gp[1];
  }
#pragma unroll
  for (int it = 0; it < 4; ++it) {
    int cid = it * 256 + tid;
    int row = cid >> 4, c = cid & 15;
    float4 f0 = f[2 * it], f1 = f[2 * it + 1];
    v8s a;
    a[0] = (short)f2bs(f0.x); a[1] = (short)f2bs(f0.y);
    a[2] = (short)f2bs(f0.z); a[3] = (short)f2bs(f0.w);
    a[4] = (short)f2bs(f1.x); a[5] = (short)f2bs(f1.y);
    a[6] = (short)f2bs(f1.z); a[7] = (short)f2bs(f1.w);
    *(v8s*)(&xs[row * STR + c * 8]) = a;
  }
  __syncthreads();

  int w = tid >> 6, lane = tid & 63;
  int m = lane & 15, quad = lane >> 4;

  v8s afrag[4];
#pragma unroll
  for (int t = 0; t < 4; ++t)
    afrag[t] = *(const v8s*)(&xs[(w * 16 + m) * STR + t * 32 + quad * 8]);

  v4f acc[9];
#pragma unroll
  for (int nt = 0; nt < 9; ++nt) {
    v4f a0 = {0.f, 0.f, 0.f, 0.f};
    const unsigned short* brow = wt + (size_t)(nt * 16 + m) * STR;
#pragma unroll
    for (int t = 0; t < 4; ++t) {
      v8s b = *(const v8s*)(brow + t * 32 + quad * 8);
      a0 = __builtin_amdgcn_mfma_f32_16x16x32_bf16(afrag[t], b, a0, 0, 0, 0);
    }
    acc[nt] = a0;
  }

#pragma unroll
  for (int r = 0; r < 4; ++r) {
    int orow = rbase + w * 16 + quad * 4 + r;
    if (orow < N_NODES) {
      if (m < 4) a_s[(size_t)orow * 4 + m] = acc[8][r];
      else if (m < 8) a_d[(size_t)orow * 4 + m - 4] = acc[8][r];
    }
  }

  __syncthreads();
#pragma unroll
  for (int nt = 0; nt < 8; ++nt)
#pragma unroll
    for (int r = 0; r < 4; ++r)
      xs[(w * 16 + quad * 4 + r) * STR + nt * 16 + m] = f2bs(acc[nt][r]);
  asm volatile("s_waitcnt lgkmcnt(0)" ::: "memory");
#pragma unroll
  for (int j = 0; j < 4; ++j) {
    int fr = 4 * j + (lane >> 4);
    int fc = (lane & 15) * 8;
    int grow = rbase + w * 16 + fr;
    v8s v = *(const v8s*)(&xs[(w * 16 + fr) * STR + fc]);
    if (grow < N_NODES) *(v8s*)(&Wx[(size_t)grow * 128 + fc]) = v;
  }
}

// ---------------- degree count (needed dsts only; distributed atomics) --------
// NOTE (R7 post-mortem): do NOT funnel compaction through a single global
// counter here — 25k same-address wave atomics serialized at ~28cy each
// (290 us). deg[dst] atomics spread over ~28k addresses are fine.
__global__ __launch_bounds__(256) void k_deg(const int* __restrict__ ei,
                                             const unsigned char* __restrict__ needed,
                                             int* __restrict__ deg) {
  int e = blockIdx.x * 256 + threadIdx.x;
  if (e >= N_EDGES) return;
  int dst = ei[N_EDGES + e];
  if (needed[dst]) atomicAdd(&deg[dst], 1);
}

// ---------------- two-level scan ----------------
__global__ __launch_bounds__(256) void k_scan1(const int* __restrict__ deg,
                                               int* __restrict__ row_start,
                                               int* __restrict__ bsum) {
  __shared__ int s[256];
  int tid = threadIdx.x;
  int i = blockIdx.x * 256 + tid;
  int v = (i < N_NODES) ? deg[i] : 0;
  s[tid] = v;
  __syncthreads();
#pragma unroll
  for (int off = 1; off < 256; off <<= 1) {
    int t = 0;
    if (tid >= off) t = s[tid - off];
    __syncthreads();
    s[tid] += t;
    __syncthreads();
  }
  if (i < N_NODES) row_start[i] = s[tid] - v;
  if (tid == 255) bsum[blockIdx.x] = s[255];
}

__global__ __launch_bounds__(512) void k_scan2(int* __restrict__ bsum,
                                               int* __restrict__ row_start) {
  __shared__ int s[512];
  int tid = threadIdx.x;
  int v = (tid < SCAN_B) ? bsum[tid] : 0;
  s[tid] = v;
  __syncthreads();
#pragma unroll
  for (int off = 1; off < 512; off <<= 1) {
    int t = 0;
    if (tid >= off) t = s[tid - off];
    __syncthreads();
    s[tid] += t;
    __syncthreads();
  }
  if (tid < SCAN_B) bsum[tid] = s[tid] - v;
  if (tid == SCAN_B - 1) row_start[N_NODES] = s[tid];
}

__global__ __launch_bounds__(256) void k_scan3(int* __restrict__ row_start,
                                               int* __restrict__ cursor,
                                               const int* __restrict__ bsum,
                                               const unsigned char* __restrict__ needed,
                                               int* __restrict__ nlist,
                                               int* __restrict__ nw_cnt) {
  int i = blockIdx.x * 256 + threadIdx.x;
  if (i >= N_NODES) return;
  int v = row_start[i] + bsum[blockIdx.x];
  row_start[i] = v;
  cursor[i] = v;
  if (needed[i]) {
    int p = atomicAdd(nw_cnt, 1);
    nlist[p] = i;
  }
}

// ---------------- scatter srcs into CSR (4B/edge; weights recomputed in agg) --
__global__ __launch_bounds__(256) void k_scatter(const int* __restrict__ ei,
                                                 const unsigned char* __restrict__ needed,
                                                 int* __restrict__ cursor,
                                                 int* __restrict__ srclist) {
  int e = blockIdx.x * 256 + threadIdx.x;
  if (e >= N_EDGES) return;
  int dst = ei[N_EDGES + e];
  if (!needed[dst]) return;
  int pos = atomicAdd(&cursor[dst], 1);
  srclist[pos] = ei[e];
}

// ---------------- per-dst aggregation: weights computed in preload ------------
__global__ __launch_bounds__(256) void k_agg(const float* __restrict__ a_s,
                                             const float* __restrict__ a_d,
                                             const unsigned short* __restrict__ Wx,
                                             const int* __restrict__ nlist,
                                             const int* __restrict__ nw_cnt,
                                             const int* __restrict__ row_start,
                                             const int* __restrict__ srclist,
                                             const float* __restrict__ bias,
                                             unsigned short* __restrict__ hout) {
  __shared__ int sS[4][64];
  __shared__ float sW[4][256];
  int w = threadIdx.x >> 6, lane = threadIdx.x & 63;
  int wid = blockIdx.x * 4 + w;
  int cnt = nw_cnt[0];
  bool act = wid < cnt;
  int dst = 0, start = 0, deg = 0;
  float4 w4 = {0.f, 0.f, 0.f, 0.f};
  float4 ad4 = {0.f, 0.f, 0.f, 0.f};
  if (act) {
    dst = nlist[wid];
    start = row_start[dst];
    deg = row_start[dst + 1] - start;
    ad4 = *(const float4*)(a_d + (size_t)dst * 4);
    if (lane < deg && lane < 64) {
      int sv = srclist[start + lane];
      float4 as = *(const float4*)(a_s + (size_t)sv * 4);
      float e0 = as.x + ad4.x; e0 = e0 > 0.f ? e0 : 0.2f * e0;
      float e1 = as.y + ad4.y; e1 = e1 > 0.f ? e1 : 0.2f * e1;
      float e2 = as.z + ad4.z; e2 = e2 > 0.f ? e2 : 0.2f * e2;
      float e3 = as.w + ad4.w; e3 = e3 > 0.f ? e3 : 0.2f * e3;
      w4.x = __expf(e0); w4.y = __expf(e1);
      w4.z = __expf(e2); w4.w = __expf(e3);
      sS[w][lane] = sv;
      *(float4*)(&sW[w][lane * 4]) = w4;
    }
  }
  __syncthreads();
  if (!act) return;

  int half = lane >> 5, li = lane & 31, hh = li >> 3;
  int nE = deg < 64 ? deg : 64;

  float4 denv = w4;
  for (int i = start + 64 + lane; i < start + deg; i += 64) {
    int sv = srclist[i];
    float4 as = *(const float4*)(a_s + (size_t)sv * 4);
    float e0 = as.x + ad4.x; e0 = e0 > 0.f ? e0 : 0.2f * e0;
    float e1 = as.y + ad4.y; e1 = e1 > 0.f ? e1 : 0.2f * e1;
    float e2 = as.z + ad4.z; e2 = e2 > 0.f ? e2 : 0.2f * e2;
    float e3 = as.w + ad4.w; e3 = e3 > 0.f ? e3 : 0.2f * e3;
    denv.x += __expf(e0); denv.y += __expf(e1);
    denv.z += __expf(e2); denv.w += __expf(e3);
  }
#pragma unroll
  for (int o = 32; o >= 1; o >>= 1) {
    denv.x += __shfl_xor(denv.x, o);
    denv.y += __shfl_xor(denv.y, o);
    denv.z += __shfl_xor(denv.z, o);
    denv.w += __shfl_xor(denv.w, o);
  }

  float4 as4 = *(const float4*)(a_s + (size_t)dst * 4);
  float s0 = as4.x + ad4.x; s0 = s0 > 0.f ? s0 : 0.2f * s0;
  float s1 = as4.y + ad4.y; s1 = s1 > 0.f ? s1 : 0.2f * s1;
  float s2 = as4.z + ad4.z; s2 = s2 > 0.f ? s2 : 0.2f * s2;
  float s3 = as4.w + ad4.w; s3 = s3 > 0.f ? s3 : 0.2f * s3;
  float w0 = __expf(s0), w1 = __expf(s1), w2 = __expf(s2), w3 = __expf(s3);
  float wSelf = hh < 2 ? (hh == 0 ? w0 : w1) : (hh == 2 ? w2 : w3);
  float denE = hh < 2 ? (hh == 0 ? denv.x : denv.y) : (hh == 2 ? denv.z : denv.w);
  float den = denE + wSelf;

  float acc0 = 0.f, acc1 = 0.f, acc2 = 0.f, acc3 = 0.f;
  if (half == 0) {
    uint2 u = *(const uint2*)(Wx + (size_t)dst * 128 + li * 4);
    acc0 = wSelf * bs2f(u.x); acc1 = wSelf * bs2f(u.x >> 16);
    acc2 = wSelf * bs2f(u.y); acc3 = wSelf * bs2f(u.y >> 16);
  }

  int j = 0;
#pragma unroll 2
  for (; j + 1 < nE; j += 2) {
    int jj = j + half;
    int s = sS[w][jj];
    float wA = sW[w][jj * 4 + hh];
    uint2 u = *(const uint2*)(Wx + (size_t)s * 128 + li * 4);
    acc0 += wA * bs2f(u.x); acc1 += wA * bs2f(u.x >> 16);
    acc2 += wA * bs2f(u.y); acc3 += wA * bs2f(u.y >> 16);
  }
  if (j < nE && half == 0) {
    int s = sS[w][j];
    float wA = sW[w][j * 4 + hh];
    uint2 u = *(const uint2*)(Wx + (size_t)s * 128 + li * 4);
    acc0 += wA * bs2f(u.x); acc1 += wA * bs2f(u.x >> 16);
    acc2 += wA * bs2f(u.y); acc3 += wA * bs2f(u.y >> 16);
  }
  for (int t = 64; t < deg; ++t) {
    if (half == 0) {
      int s = srclist[start + t];
      float4 as = *(const float4*)(a_s + (size_t)s * 4);
      float ee = (hh == 0 ? as.x + ad4.x : hh == 1 ? as.y + ad4.y
                : hh == 2 ? as.z + ad4.z : as.w + ad4.w);
      ee = ee > 0.f ? ee : 0.2f * ee;
      float wA = __expf(ee);
      uint2 u = *(const uint2*)(Wx + (size_t)s * 128 + li * 4);
      acc0 += wA * bs2f(u.x); acc1 += wA * bs2f(u.x >> 16);
      acc2 += wA * bs2f(u.y); acc3 += wA * bs2f(u.y >> 16);
    }
  }

  acc0 += __shfl_xor(acc0, 32);
  acc1 += __shfl_xor(acc1, 32);
  acc2 += __shfl_xor(acc2, 32);
  acc3 += __shfl_xor(acc3, 32);

  if (half == 0) {
    float inv = 1.0f / den;
    float4 b4 = *(const float4*)(bias + li * 4);
    float r0 = acc0 * inv + b4.x;
    float r1 = acc1 * inv + b4.y;
    float r2 = acc2 * inv + b4.z;
    float r3 = acc3 * inv + b4.w;
    uint2 o;
    o.x = (unsigned int)f2bs(r0) | ((unsigned int)f2bs(r1) << 16);
    o.y = (unsigned int)f2bs(r2) | ((unsigned int)f2bs(r3) << 16);
    *(uint2*)(hout + (size_t)dst * 128 + li * 4) = o;
  }
}

// ---------------- fused: msg = message @ fc_w^T + fc_b, then scoring ----------
__global__ __launch_bounds__(256) void k_msgscore(const float* __restrict__ message,
                                                  const float* __restrict__ fc_w,
                                                  const float* __restrict__ fc_b,
                                                  const unsigned short* __restrict__ h,
                                                  const int* __restrict__ indices,
                                                  float* __restrict__ out) {
  __shared__ float Sm[16][256];
  float* red = &Sm[0][0];
  int tid = threadIdx.x;
  int b0 = blockIdx.x * 16;
  for (int i = tid; i < 16 * 256; i += 256)
    Sm[i >> 8][i & 255] = message[(size_t)b0 * 256 + i];
  __syncthreads();
  int e = tid & 127, half = tid >> 7;
  float acc[16];
#pragma unroll
  for (int r = 0; r < 16; ++r) acc[r] = 0.f;
  const float* wrow = fc_w + (size_t)e * 256 + half * 128;
  for (int k = 0; k < 128; k += 4) {
    float4 w4 = *(const float4*)(wrow + k);
#pragma unroll
    for (int r = 0; r < 16; ++r) {
      float4 m4 = *(const float4*)(&Sm[r][half * 128 + k]);
      acc[r] += m4.x * w4.x + m4.y * w4.y + m4.z * w4.z + m4.w * w4.w;
    }
  }
  __syncthreads();
  if (half == 0) {
#pragma unroll
    for (int r = 0; r < 16; ++r) red[r * 128 + e] = acc[r];
  }
  __syncthreads();
  if (half == 1) {
#pragma unroll
    for (int r = 0; r < 16; ++r) red[r * 128 + e] += acc[r];
  }
  __syncthreads();
  for (int i = tid; i < 2048; i += 256) red[i] += fc_b[i & 127];
  __syncthreads();

  int r = tid >> 4, c = tid & 15;
  int idx = indices[(b0 + r) * 16 + c];
  const unsigned short* hr = h + (size_t)idx * 128;
  const float* mr = red + r * 128;
  float dot = 0.f;
#pragma unroll
  for (int k = 0; k < 128; k += 8) {
    uint4 q = *(const uint4*)(hr + k);
    float4 m0 = *(const float4*)(mr + k);
    float4 m1 = *(const float4*)(mr + k + 4);
    dot += bs2f(q.x) * m0.x + bs2f(q.x >> 16) * m0.y
         + bs2f(q.y) * m0.z + bs2f(q.y >> 16) * m0.w
         + bs2f(q.z) * m1.x + bs2f(q.z >> 16) * m1.y
         + bs2f(q.w) * m1.z + bs2f(q.w >> 16) * m1.w;
  }
  float mx = dot;
#pragma unroll
  for (int o = 1; o < 16; o <<= 1) mx = fmaxf(mx, __shfl_xor(mx, o));
  float ex = __expf(dot - mx);
  float sum = ex;
#pragma unroll
  for (int o = 1; o < 16; o <<= 1) sum += __shfl_xor(sum, o);
  float lse = mx + __logf(sum);
  out[(b0 + r) * 16 + c] = dot - lse;
}

extern "C" void kernel_launch(void* const* d_in, const int* in_sizes, int n_in,
                              void* d_out, int out_size, void* d_ws, size_t ws_size,
                              hipStream_t stream) {
  (void)in_sizes; (void)n_in; (void)out_size; (void)ws_size;
  const float* message = (const float*)d_in[0];
  const float* x       = (const float*)d_in[1];
  const int*   ei      = (const int*)d_in[2];
  const int*   indices = (const int*)d_in[3];
  const float* W       = (const float*)d_in[4];
  const float* att_src = (const float*)d_in[5];
  const float* att_dst = (const float*)d_in[6];
  const float* bias    = (const float*)d_in[7];
  const float* fc_w    = (const float*)d_in[8];
  const float* fc_b    = (const float*)d_in[9];
  float* out = (float*)d_out;

  char* p = (char*)d_ws;
  auto alloc = [&](size_t bytes) -> char* {
    char* r = p;
    p += (bytes + 255) & ~(size_t)255;
    return r;
  };
  unsigned short* Wx = (unsigned short*)alloc((size_t)N_NODES * 128 * 2);
  unsigned short* h  = (unsigned short*)alloc((size_t)N_NODES * 128 * 2);
  float* a_s = (float*)alloc((size_t)N_NODES * 4 * 4);
  float* a_d = (float*)alloc((size_t)N_NODES * 4 * 4);
  unsigned short* Wtp = (unsigned short*)alloc((size_t)WTROWS * STR * 2);
  // ---- zeroed region: needed .. nw_cnt (one memset) ----
  unsigned char* needed = (unsigned char*)alloc((size_t)N_NODES);
  int* deg       = (int*)alloc((size_t)N_NODES * 4);
  int* nw_cnt    = (int*)alloc(4);
  // ---- end zeroed region ----
  int* row_start = (int*)alloc(((size_t)N_NODES + 1) * 4);
  int* cursor    = (int*)alloc((size_t)N_NODES * 4);
  int* bsum      = (int*)alloc((size_t)SCAN_B * 4);
  int* nlist     = (int*)alloc((size_t)MAXNEED * 4);
  int* srclist   = (int*)alloc((size_t)N_EDGES * 4);

  hipMemsetAsync(needed, 0, (size_t)((char*)row_start - (char*)needed), stream);

  k_prep<<<128, 256, 0, stream>>>(W, att_src, att_dst, Wtp, indices, needed);
  k_wx<<<WXBLOCKS, 256, 0, stream>>>(x, Wtp, Wx, a_s, a_d);
  k_deg<<<N_EDGES / 256, 256, 0, stream>>>(ei, needed, deg);
  k_scan1<<<SCAN_B, 256, 0, stream>>>(deg, row_start, bsum);
  k_scan2<<<1, 512, 0, stream>>>(bsum, row_start);
  k_scan3<<<SCAN_B, 256, 0, stream>>>(row_start, cursor, bsum, needed, nlist, nw_cnt);
  k_scatter<<<N_EDGES / 256, 256, 0, stream>>>(ei, needed, cursor, srclist);
  k_agg<<<MAXNEED / 4, 256, 0, stream>>>(a_s, a_d, Wx, nlist, nw_cnt, row_start, srclist, bias, h);
  k_msgscore<<<BATCH / 16, 256, 0, stream>>>(message, fc_w, fc_b, h, indices, out);
}

// Round 9
// 212.201 us; speedup vs baseline: 2.3964x; 1.1377x over previous
//
#include <hip/hip_runtime.h>
#include <stdint.h>
#include <stddef.h>

#define N_NODES 100000
#define N_EDGES 1600000
#define F_IN 128
#define EMB 128
#define HEADS 4
#define D_HEAD 32
#define HIDDEN 256
#define BATCH 2048
#define CANDS 16
#define NODE_B 391    /* ceil(N_NODES/256) */
#define MAXNEED 32768 /* BATCH*CANDS upper bound on unique needed dsts */
#define WXBLOCKS 782  /* ceil(N_NODES/128) */
#define WTROWS 144    /* 128 W cols + 8 att-projection rows + 8 zero pad */
#define STR 136       /* padded row stride (shorts) */

typedef __attribute__((ext_vector_type(8))) short v8s;
typedef __attribute__((ext_vector_type(4))) float v4f;

__device__ __forceinline__ unsigned short f2bs(float f) {
  unsigned int u = __builtin_bit_cast(unsigned int, f);
  u = (u + 0x7fffu + ((u >> 16) & 1u)) >> 16;
  return (unsigned short)u;
}
__device__ __forceinline__ float bs2f(unsigned int s) {
  unsigned int u = (s & 0xffffu) << 16;
  return __builtin_bit_cast(float, u);
}

// ---------------- prep: padded Wt^T (+att-projection rows) + mark needed -------
__global__ __launch_bounds__(256) void k_prep(const float* __restrict__ W,
                                              const float* __restrict__ att_src,
                                              const float* __restrict__ att_dst,
                                              unsigned short* __restrict__ Wtp,
                                              const int* __restrict__ idx,
                                              unsigned char* __restrict__ needed) {
  int i = blockIdx.x * 256 + threadIdx.x;
  if (i < 128 * STR) {
    int r = i / STR, c = i - r * STR;
    Wtp[i] = (c < 128) ? f2bs(W[c * 128 + r]) : (unsigned short)0;
  } else if (i < WTROWS * STR) {
    int ii = i - 128 * STR;
    int r = ii / STR, c = ii - r * STR;  // r: 0..15
    unsigned short v = 0;
    if (c < 128 && r < 8) {
      const float* att = (r < 4) ? att_src : att_dst;
      int hh = r & 3;
      float s = 0.f;
#pragma unroll
      for (int d = 0; d < 32; ++d) s += W[c * 128 + hh * 32 + d] * att[hh * 32 + d];
      v = f2bs(s);
    }
    Wtp[i] = v;
  }
  if (i < BATCH * CANDS) needed[idx[i]] = 1;
}

// ---------------- compact needed nodes: nidx[dst]=ni+1, nlist[ni]=dst ----------
// Per-thread atomicAdd on one counter is wave-coalesced by the compiler
// (~1.5k actual atomic ops) — unlike R7's 25k manual leader atomics.
__global__ __launch_bounds__(256) void k_compact(const unsigned char* __restrict__ needed,
                                                 int* __restrict__ nidx,
                                                 int* __restrict__ nlist,
                                                 int* __restrict__ nw_cnt) {
  int i = blockIdx.x * 256 + threadIdx.x;
  if (i >= N_NODES) return;
  if (needed[i]) {
    int p = atomicAdd(nw_cnt, 1);
    nidx[i] = p + 1;
    nlist[p] = i;
  }
}

// ---------------- Wx = x @ W (MFMA), Wt staged in LDS once per 128 rows --------
__global__ __launch_bounds__(256) void k_wx(const float* __restrict__ x,
                                            const unsigned short* __restrict__ Wtp,
                                            unsigned short* __restrict__ Wx,
                                            float* __restrict__ a_s,
                                            float* __restrict__ a_d) {
  __shared__ unsigned short wt[WTROWS * STR];  // 39168 B
  __shared__ unsigned short xs[64 * STR];      // 17408 B
  int tid = threadIdx.x;

  // stage Wtp -> LDS once (reused by both 64-row chunks)
  {
    const uint4* s = (const uint4*)Wtp;
    uint4* d = (uint4*)wt;
#pragma unroll
    for (int it = 0; it < 10; ++it) {
      int i = it * 256 + tid;
      if (i < WTROWS * STR / 8) d[i] = s[i];
    }
  }

  int w = tid >> 6, lane = tid & 63;
  int m = lane & 15, quad = lane >> 4;

  for (int chunk = 0; chunk < 2; ++chunk) {
    int rbase = blockIdx.x * 128 + chunk * 64;

    // stage x: hoist all 8 loads, then convert+write
    float4 f[8];
#pragma unroll
    for (int it = 0; it < 4; ++it) {
      int cid = it * 256 + tid;
      int row = cid >> 4, c = cid & 15;
      int gr = rbase + row;
      if (gr >= N_NODES) gr = N_NODES - 1;
      const float4* gp = (const float4*)(x + (size_t)gr * 128 + c * 8);
      f[2 * it] = gp[0];
      f[2 * it + 1] = gp[1];
    }
#pragma unroll
    for (int it = 0; it < 4; ++it) {
      int cid = it * 256 + tid;
      int row = cid >> 4, c = cid & 15;
      float4 f0 = f[2 * it], f1 = f[2 * it + 1];
      v8s a;
      a[0] = (short)f2bs(f0.x); a[1] = (short)f2bs(f0.y);
      a[2] = (short)f2bs(f0.z); a[3] = (short)f2bs(f0.w);
      a[4] = (short)f2bs(f1.x); a[5] = (short)f2bs(f1.y);
      a[6] = (short)f2bs(f1.z); a[7] = (short)f2bs(f1.w);
      *(v8s*)(&xs[row * STR + c * 8]) = a;
    }
    __syncthreads();

    v8s afrag[4];
#pragma unroll
    for (int t = 0; t < 4; ++t)
      afrag[t] = *(const v8s*)(&xs[(w * 16 + m) * STR + t * 32 + quad * 8]);

    v4f acc[9];
#pragma unroll
    for (int nt = 0; nt < 9; ++nt) {
      v4f a0 = {0.f, 0.f, 0.f, 0.f};
      const unsigned short* brow = wt + (size_t)(nt * 16 + m) * STR;
#pragma unroll
      for (int t = 0; t < 4; ++t) {
        v8s b = *(const v8s*)(brow + t * 32 + quad * 8);
        a0 = __builtin_amdgcn_mfma_f32_16x16x32_bf16(afrag[t], b, a0, 0, 0, 0);
      }
      acc[nt] = a0;
    }

    // a_s/a_d from projection tile nt=8
#pragma unroll
    for (int r = 0; r < 4; ++r) {
      int orow = rbase + w * 16 + quad * 4 + r;
      if (orow < N_NODES) {
        if (m < 4) a_s[(size_t)orow * 4 + m] = acc[8][r];
        else if (m < 8) a_d[(size_t)orow * 4 + m - 4] = acc[8][r];
      }
    }

    // C scatter into own wave's LDS rows, then coalesced store
    __syncthreads();
#pragma unroll
    for (int nt = 0; nt < 8; ++nt)
#pragma unroll
      for (int r = 0; r < 4; ++r)
        xs[(w * 16 + quad * 4 + r) * STR + nt * 16 + m] = f2bs(acc[nt][r]);
    asm volatile("s_waitcnt lgkmcnt(0)" ::: "memory");
#pragma unroll
    for (int j = 0; j < 4; ++j) {
      int fr = 4 * j + (lane >> 4);
      int fc = (lane & 15) * 8;
      int grow = rbase + w * 16 + fr;
      v8s v = *(const v8s*)(&xs[(w * 16 + fr) * STR + fc]);
      if (grow < N_NODES) *(v8s*)(&Wx[(size_t)grow * 128 + fc]) = v;
    }
    __syncthreads();  // epilogue xs reads done before next chunk restages
  }
}

// ---------------- scatter srcs into fixed 64-slot buckets (no CSR build) ------
// Distributed atomics over ~28k cnt addresses (R7 lesson: never one address).
__global__ __launch_bounds__(256) void k_scatter(const int* __restrict__ ei,
                                                 const int* __restrict__ nidx,
                                                 int* __restrict__ cnt,
                                                 int* __restrict__ srclist) {
  int e = blockIdx.x * 256 + threadIdx.x;
  if (e >= N_EDGES) return;
  int dst = ei[N_EDGES + e];
  int ni = nidx[dst];
  if (!ni) return;
  ni--;
  int pos = atomicAdd(&cnt[ni], 1);
  if (pos < 64) srclist[ni * 64 + pos] = ei[e];
}

// ---------------- per-dst aggregation over 64-slot buckets --------------------
__global__ __launch_bounds__(256) void k_agg(const float* __restrict__ a_s,
                                             const float* __restrict__ a_d,
                                             const unsigned short* __restrict__ Wx,
                                             const int* __restrict__ nlist,
                                             const int* __restrict__ nw_cnt,
                                             const int* __restrict__ cnt,
                                             const int* __restrict__ srclist,
                                             const int* __restrict__ ei,
                                             const float* __restrict__ bias,
                                             unsigned short* __restrict__ hout) {
  __shared__ int sS[4][64];
  __shared__ float sW[4][256];
  int w = threadIdx.x >> 6, lane = threadIdx.x & 63;
  int wid = blockIdx.x * 4 + w;
  bool act = wid < nw_cnt[0];
  int dst = 0, degRaw = 0, deg = 0;
  float4 w4 = {0.f, 0.f, 0.f, 0.f};
  float4 ad4 = {0.f, 0.f, 0.f, 0.f};
  if (act) {
    dst = nlist[wid];
    degRaw = cnt[wid];
    deg = degRaw < 64 ? degRaw : 64;
    ad4 = *(const float4*)(a_d + (size_t)dst * 4);
    if (lane < deg) {
      int sv = srclist[wid * 64 + lane];
      float4 as = *(const float4*)(a_s + (size_t)sv * 4);
      float e0 = as.x + ad4.x; e0 = e0 > 0.f ? e0 : 0.2f * e0;
      float e1 = as.y + ad4.y; e1 = e1 > 0.f ? e1 : 0.2f * e1;
      float e2 = as.z + ad4.z; e2 = e2 > 0.f ? e2 : 0.2f * e2;
      float e3 = as.w + ad4.w; e3 = e3 > 0.f ? e3 : 0.2f * e3;
      w4.x = __expf(e0); w4.y = __expf(e1);
      w4.z = __expf(e2); w4.w = __expf(e3);
      sS[w][lane] = sv;
      *(float4*)(&sW[w][lane * 4]) = w4;
    }
  }
  __syncthreads();
  if (!act) return;

  float4 as4 = *(const float4*)(a_s + (size_t)dst * 4);
  float s0 = as4.x + ad4.x; s0 = s0 > 0.f ? s0 : 0.2f * s0;
  float s1 = as4.y + ad4.y; s1 = s1 > 0.f ? s1 : 0.2f * s1;
  float s2 = as4.z + ad4.z; s2 = s2 > 0.f ? s2 : 0.2f * s2;
  float s3 = as4.w + ad4.w; s3 = s3 > 0.f ? s3 : 0.2f * s3;
  float w0 = __expf(s0), w1 = __expf(s1), w2 = __expf(s2), w3 = __expf(s3);

  if (degRaw > 64) {
    // ---- correctness-only fallback (P ~ 1e-20): full edge rescan ----
    // layout: lane -> cols {2*lane, 2*lane+1}, head hh2 = lane>>4
    int hh2 = lane >> 4;
    float adH = hh2 < 2 ? (hh2 == 0 ? ad4.x : ad4.y) : (hh2 == 2 ? ad4.z : ad4.w);
    float4 dv = {0.f, 0.f, 0.f, 0.f};
    for (int e = lane; e < N_EDGES; e += 64) {
      if (ei[N_EDGES + e] == dst) {
        int sv = ei[e];
        float4 as = *(const float4*)(a_s + (size_t)sv * 4);
        float e0 = as.x + ad4.x; e0 = e0 > 0.f ? e0 : 0.2f * e0;
        float e1 = as.y + ad4.y; e1 = e1 > 0.f ? e1 : 0.2f * e1;
        float e2 = as.z + ad4.z; e2 = e2 > 0.f ? e2 : 0.2f * e2;
        float e3 = as.w + ad4.w; e3 = e3 > 0.f ? e3 : 0.2f * e3;
        dv.x += __expf(e0); dv.y += __expf(e1);
        dv.z += __expf(e2); dv.w += __expf(e3);
      }
    }
#pragma unroll
    for (int o = 32; o >= 1; o >>= 1) {
      dv.x += __shfl_xor(dv.x, o); dv.y += __shfl_xor(dv.y, o);
      dv.z += __shfl_xor(dv.z, o); dv.w += __shfl_xor(dv.w, o);
    }
    float wSelfH = hh2 < 2 ? (hh2 == 0 ? w0 : w1) : (hh2 == 2 ? w2 : w3);
    float den = wSelfH + (hh2 < 2 ? (hh2 == 0 ? dv.x : dv.y)
                                  : (hh2 == 2 ? dv.z : dv.w));
    unsigned int us = *(const unsigned int*)(Wx + (size_t)dst * 128 + 2 * lane);
    float accP = wSelfH * bs2f(us), accQ = wSelfH * bs2f(us >> 16);
    for (int base = 0; base < N_EDGES; base += 64) {
      int e = base + lane;
      bool mm = (e < N_EDGES) && (ei[N_EDGES + e] == dst);
      unsigned long long mask = __ballot(mm);
      int svL = mm ? ei[e] : 0;
      while (mask) {
        int b = __ffsll(mask) - 1;
        mask &= mask - 1;
        int sv = __shfl(svL, b);
        float ash = a_s[(size_t)sv * 4 + hh2];
        float ee = ash + adH; ee = ee > 0.f ? ee : 0.2f * ee;
        float wA = __expf(ee);
        unsigned int u = *(const unsigned int*)(Wx + (size_t)sv * 128 + 2 * lane);
        accP += wA * bs2f(u); accQ += wA * bs2f(u >> 16);
      }
    }
    float inv = 1.0f / den;
    float2 b2 = *(const float2*)(bias + 2 * lane);
    unsigned int packed = (unsigned int)f2bs(accP * inv + b2.x)
                        | ((unsigned int)f2bs(accQ * inv + b2.y) << 16);
    *(unsigned int*)(hout + (size_t)dst * 128 + 2 * lane) = packed;
    return;
  }

  int half = lane >> 5, li = lane & 31, hh = li >> 3;

  // denominator: butterfly over preloaded weights (deg <= 64 guaranteed here)
  float4 denv = w4;
#pragma unroll
  for (int o = 32; o >= 1; o >>= 1) {
    denv.x += __shfl_xor(denv.x, o);
    denv.y += __shfl_xor(denv.y, o);
    denv.z += __shfl_xor(denv.z, o);
    denv.w += __shfl_xor(denv.w, o);
  }
  float wSelf = hh < 2 ? (hh == 0 ? w0 : w1) : (hh == 2 ? w2 : w3);
  float denE = hh < 2 ? (hh == 0 ? denv.x : denv.y) : (hh == 2 ? denv.z : denv.w);
  float den = denE + wSelf;

  float acc0 = 0.f, acc1 = 0.f, acc2 = 0.f, acc3 = 0.f;
  if (half == 0) {
    uint2 u = *(const uint2*)(Wx + (size_t)dst * 128 + li * 4);
    acc0 = wSelf * bs2f(u.x); acc1 = wSelf * bs2f(u.x >> 16);
    acc2 = wSelf * bs2f(u.y); acc3 = wSelf * bs2f(u.y >> 16);
  }

  int j = 0;
#pragma unroll 4
  for (; j + 1 < deg; j += 2) {
    int jj = j + half;
    int s = sS[w][jj];
    float wA = sW[w][jj * 4 + hh];
    uint2 u = *(const uint2*)(Wx + (size_t)s * 128 + li * 4);
    acc0 += wA * bs2f(u.x); acc1 += wA * bs2f(u.x >> 16);
    acc2 += wA * bs2f(u.y); acc3 += wA * bs2f(u.y >> 16);
  }
  if (j < deg && half == 0) {
    int s = sS[w][j];
    float wA = sW[w][j * 4 + hh];
    uint2 u = *(const uint2*)(Wx + (size_t)s * 128 + li * 4);
    acc0 += wA * bs2f(u.x); acc1 += wA * bs2f(u.x >> 16);
    acc2 += wA * bs2f(u.y); acc3 += wA * bs2f(u.y >> 16);
  }

  acc0 += __shfl_xor(acc0, 32);
  acc1 += __shfl_xor(acc1, 32);
  acc2 += __shfl_xor(acc2, 32);
  acc3 += __shfl_xor(acc3, 32);

  if (half == 0) {
    float inv = 1.0f / den;
    float4 b4 = *(const float4*)(bias + li * 4);
    float r0 = acc0 * inv + b4.x;
    float r1 = acc1 * inv + b4.y;
    float r2 = acc2 * inv + b4.z;
    float r3 = acc3 * inv + b4.w;
    uint2 o;
    o.x = (unsigned int)f2bs(r0) | ((unsigned int)f2bs(r1) << 16);
    o.y = (unsigned int)f2bs(r2) | ((unsigned int)f2bs(r3) << 16);
    *(uint2*)(hout + (size_t)dst * 128 + li * 4) = o;
  }
}

// ---------------- fused: msg = message @ fc_w^T + fc_b, then scoring ----------
__global__ __launch_bounds__(256) void k_msgscore(const float* __restrict__ message,
                                                  const float* __restrict__ fc_w,
                                                  const float* __restrict__ fc_b,
                                                  const unsigned short* __restrict__ h,
                                                  const int* __restrict__ indices,
                                                  float* __restrict__ out) {
  __shared__ float Sm[16][256];
  float* red = &Sm[0][0];
  int tid = threadIdx.x;
  int b0 = blockIdx.x * 16;
  for (int i = tid; i < 16 * 256; i += 256)
    Sm[i >> 8][i & 255] = message[(size_t)b0 * 256 + i];
  __syncthreads();
  int e = tid & 127, half = tid >> 7;
  float acc[16];
#pragma unroll
  for (int r = 0; r < 16; ++r) acc[r] = 0.f;
  const float* wrow = fc_w + (size_t)e * 256 + half * 128;
  for (int k = 0; k < 128; k += 4) {
    float4 w4 = *(const float4*)(wrow + k);
#pragma unroll
    for (int r = 0; r < 16; ++r) {
      float4 m4 = *(const float4*)(&Sm[r][half * 128 + k]);
      acc[r] += m4.x * w4.x + m4.y * w4.y + m4.z * w4.z + m4.w * w4.w;
    }
  }
  __syncthreads();
  if (half == 0) {
#pragma unroll
    for (int r = 0; r < 16; ++r) red[r * 128 + e] = acc[r];
  }
  __syncthreads();
  if (half == 1) {
#pragma unroll
    for (int r = 0; r < 16; ++r) red[r * 128 + e] += acc[r];
  }
  __syncthreads();
  for (int i = tid; i < 2048; i += 256) red[i] += fc_b[i & 127];
  __syncthreads();

  int r = tid >> 4, c = tid & 15;
  int idx = indices[(b0 + r) * 16 + c];
  const unsigned short* hr = h + (size_t)idx * 128;
  const float* mr = red + r * 128;
  float dot = 0.f;
#pragma unroll
  for (int k = 0; k < 128; k += 8) {
    uint4 q = *(const uint4*)(hr + k);
    float4 m0 = *(const float4*)(mr + k);
    float4 m1 = *(const float4*)(mr + k + 4);
    dot += bs2f(q.x) * m0.x + bs2f(q.x >> 16) * m0.y
         + bs2f(q.y) * m0.z + bs2f(q.y >> 16) * m0.w
         + bs2f(q.z) * m1.x + bs2f(q.z >> 16) * m1.y
         + bs2f(q.w) * m1.z + bs2f(q.w >> 16) * m1.w;
  }
  float mx = dot;
#pragma unroll
  for (int o = 1; o < 16; o <<= 1) mx = fmaxf(mx, __shfl_xor(mx, o));
  float ex = __expf(dot - mx);
  float sum = ex;
#pragma unroll
  for (int o = 1; o < 16; o <<= 1) sum += __shfl_xor(sum, o);
  float lse = mx + __logf(sum);
  out[(b0 + r) * 16 + c] = dot - lse;
}

extern "C" void kernel_launch(void* const* d_in, const int* in_sizes, int n_in,
                              void* d_out, int out_size, void* d_ws, size_t ws_size,
                              hipStream_t stream) {
  (void)in_sizes; (void)n_in; (void)out_size; (void)ws_size;
  const float* message = (const float*)d_in[0];
  const float* x       = (const float*)d_in[1];
  const int*   ei      = (const int*)d_in[2];
  const int*   indices = (const int*)d_in[3];
  const float* W       = (const float*)d_in[4];
  const float* att_src = (const float*)d_in[5];
  const float* att_dst = (const float*)d_in[6];
  const float* bias    = (const float*)d_in[7];
  const float* fc_w    = (const float*)d_in[8];
  const float* fc_b    = (const float*)d_in[9];
  float* out = (float*)d_out;

  char* p = (char*)d_ws;
  auto alloc = [&](size_t bytes) -> char* {
    char* r = p;
    p += (bytes + 255) & ~(size_t)255;
    return r;
  };
  unsigned short* Wx = (unsigned short*)alloc((size_t)N_NODES * 128 * 2);
  unsigned short* h  = (unsigned short*)alloc((size_t)N_NODES * 128 * 2);
  float* a_s = (float*)alloc((size_t)N_NODES * 4 * 4);
  float* a_d = (float*)alloc((size_t)N_NODES * 4 * 4);
  unsigned short* Wtp = (unsigned short*)alloc((size_t)WTROWS * STR * 2);
  // ---- zeroed region: needed .. nw_cnt (one memset) ----
  unsigned char* needed = (unsigned char*)alloc((size_t)N_NODES);
  int* nidx      = (int*)alloc((size_t)N_NODES * 4);
  int* cnt       = (int*)alloc((size_t)MAXNEED * 4);
  int* nw_cnt    = (int*)alloc(4);
  // ---- end zeroed region ----
  int* nlist     = (int*)alloc((size_t)MAXNEED * 4);
  int* srclist   = (int*)alloc((size_t)MAXNEED * 64 * 4);

  hipMemsetAsync(needed, 0, (size_t)((char*)nlist - (char*)needed), stream);

  k_prep<<<128, 256, 0, stream>>>(W, att_src, att_dst, Wtp, indices, needed);
  k_compact<<<NODE_B, 256, 0, stream>>>(needed, nidx, nlist, nw_cnt);
  k_wx<<<WXBLOCKS, 256, 0, stream>>>(x, Wtp, Wx, a_s, a_d);
  k_scatter<<<N_EDGES / 256, 256, 0, stream>>>(ei, nidx, cnt, srclist);
  k_agg<<<MAXNEED / 4, 256, 0, stream>>>(a_s, a_d, Wx, nlist, nw_cnt, cnt, srclist, ei, bias, h);
  k_msgscore<<<BATCH / 16, 256, 0, stream>>>(message, fc_w, fc_b, h, indices, out);
}

// Round 10
// 194.070 us; speedup vs baseline: 2.6203x; 1.0934x over previous
//
#include <hip/hip_runtime.h>
#include <stdint.h>
#include <stddef.h>

#define N_NODES 100000
#define N_EDGES 1600000
#define F_IN 128
#define EMB 128
#define HEADS 4
#define D_HEAD 32
#define HIDDEN 256
#define BATCH 2048
#define CANDS 16
#define MAXNEED 32768 /* BATCH*CANDS upper bound on unique needed dsts */
#define WXBLOCKS 782  /* ceil(N_NODES/128) */
#define WTROWS 144    /* 128 W cols + 8 att-projection rows + 8 zero pad */
#define STR 136       /* padded row stride (shorts) */

typedef __attribute__((ext_vector_type(8))) short v8s;
typedef __attribute__((ext_vector_type(4))) float v4f;

__device__ __forceinline__ unsigned short f2bs(float f) {
  unsigned int u = __builtin_bit_cast(unsigned int, f);
  u = (u + 0x7fffu + ((u >> 16) & 1u)) >> 16;
  return (unsigned short)u;
}
__device__ __forceinline__ float bs2f(unsigned int s) {
  unsigned int u = (s & 0xffffu) << 16;
  return __builtin_bit_cast(float, u);
}

// ------- prep: padded Wt^T (+att-projection rows) + dedup-compact needed ------
// Dedup over the 32768 indices directly (no 100k mark+scan pass):
// first toucher of node v assigns it a compact id. The nw_cnt atomic is a
// per-thread atomicAdd(p,1) -> compiler wave-coalesces it (G12/m20); the R7
// disaster was 25k MANUAL leader atomics, which defeat that coalescing.
__global__ __launch_bounds__(256) void k_prep(const float* __restrict__ W,
                                              const float* __restrict__ att_src,
                                              const float* __restrict__ att_dst,
                                              unsigned short* __restrict__ Wtp,
                                              const int* __restrict__ idx,
                                              int* __restrict__ mark,
                                              int* __restrict__ nidx,
                                              int* __restrict__ nlist,
                                              int* __restrict__ nw_cnt) {
  int i = blockIdx.x * 256 + threadIdx.x;
  if (i < 128 * STR) {
    int r = i / STR, c = i - r * STR;
    Wtp[i] = (c < 128) ? f2bs(W[c * 128 + r]) : (unsigned short)0;
  } else if (i < WTROWS * STR) {
    int ii = i - 128 * STR;
    int r = ii / STR, c = ii - r * STR;  // r: 0..15
    unsigned short v = 0;
    if (c < 128 && r < 8) {
      const float* att = (r < 4) ? att_src : att_dst;
      int hh = r & 3;
      float s = 0.f;
#pragma unroll
      for (int d = 0; d < 32; ++d) s += W[c * 128 + hh * 32 + d] * att[hh * 32 + d];
      v = f2bs(s);
    }
    Wtp[i] = v;
  }
  if (i < BATCH * CANDS) {
    int v = idx[i];
    if (atomicAdd(&mark[v], 1) == 0) {
      int p = atomicAdd(nw_cnt, 1);
      nidx[v] = p + 1;
      nlist[p] = v;
    }
  }
}

// ---------------- Wx = x @ W (MFMA), Wt staged in LDS once per 128 rows --------
__global__ __launch_bounds__(256) void k_wx(const float* __restrict__ x,
                                            const unsigned short* __restrict__ Wtp,
                                            unsigned short* __restrict__ Wx,
                                            float* __restrict__ a_s,
                                            float* __restrict__ a_d) {
  __shared__ unsigned short wt[WTROWS * STR];  // 39168 B
  __shared__ unsigned short xs[64 * STR];      // 17408 B
  int tid = threadIdx.x;

  {
    const uint4* s = (const uint4*)Wtp;
    uint4* d = (uint4*)wt;
#pragma unroll
    for (int it = 0; it < 10; ++it) {
      int i = it * 256 + tid;
      if (i < WTROWS * STR / 8) d[i] = s[i];
    }
  }

  int w = tid >> 6, lane = tid & 63;
  int m = lane & 15, quad = lane >> 4;

  for (int chunk = 0; chunk < 2; ++chunk) {
    int rbase = blockIdx.x * 128 + chunk * 64;

    float4 f[8];
#pragma unroll
    for (int it = 0; it < 4; ++it) {
      int cid = it * 256 + tid;
      int row = cid >> 4, c = cid & 15;
      int gr = rbase + row;
      if (gr >= N_NODES) gr = N_NODES - 1;
      const float4* gp = (const float4*)(x + (size_t)gr * 128 + c * 8);
      f[2 * it] = gp[0];
      f[2 * it + 1] = gp[1];
    }
#pragma unroll
    for (int it = 0; it < 4; ++it) {
      int cid = it * 256 + tid;
      int row = cid >> 4, c = cid & 15;
      float4 f0 = f[2 * it], f1 = f[2 * it + 1];
      v8s a;
      a[0] = (short)f2bs(f0.x); a[1] = (short)f2bs(f0.y);
      a[2] = (short)f2bs(f0.z); a[3] = (short)f2bs(f0.w);
      a[4] = (short)f2bs(f1.x); a[5] = (short)f2bs(f1.y);
      a[6] = (short)f2bs(f1.z); a[7] = (short)f2bs(f1.w);
      *(v8s*)(&xs[row * STR + c * 8]) = a;
    }
    __syncthreads();

    v8s afrag[4];
#pragma unroll
    for (int t = 0; t < 4; ++t)
      afrag[t] = *(const v8s*)(&xs[(w * 16 + m) * STR + t * 32 + quad * 8]);

    v4f acc[9];
#pragma unroll
    for (int nt = 0; nt < 9; ++nt) {
      v4f a0 = {0.f, 0.f, 0.f, 0.f};
      const unsigned short* brow = wt + (size_t)(nt * 16 + m) * STR;
#pragma unroll
      for (int t = 0; t < 4; ++t) {
        v8s b = *(const v8s*)(brow + t * 32 + quad * 8);
        a0 = __builtin_amdgcn_mfma_f32_16x16x32_bf16(afrag[t], b, a0, 0, 0, 0);
      }
      acc[nt] = a0;
    }

#pragma unroll
    for (int r = 0; r < 4; ++r) {
      int orow = rbase + w * 16 + quad * 4 + r;
      if (orow < N_NODES) {
        if (m < 4) a_s[(size_t)orow * 4 + m] = acc[8][r];
        else if (m < 8) a_d[(size_t)orow * 4 + m - 4] = acc[8][r];
      }
    }

    __syncthreads();
#pragma unroll
    for (int nt = 0; nt < 8; ++nt)
#pragma unroll
      for (int r = 0; r < 4; ++r)
        xs[(w * 16 + quad * 4 + r) * STR + nt * 16 + m] = f2bs(acc[nt][r]);
    asm volatile("s_waitcnt lgkmcnt(0)" ::: "memory");
#pragma unroll
    for (int j = 0; j < 4; ++j) {
      int fr = 4 * j + (lane >> 4);
      int fc = (lane & 15) * 8;
      int grow = rbase + w * 16 + fr;
      v8s v = *(const v8s*)(&xs[(w * 16 + fr) * STR + fc]);
      if (grow < N_NODES) *(v8s*)(&Wx[(size_t)grow * 128 + fc]) = v;
    }
    __syncthreads();
  }
}

// ---------------- scatter srcs into fixed 64-slot buckets ----------------------
__global__ __launch_bounds__(256) void k_scatter(const int* __restrict__ ei,
                                                 const int* __restrict__ nidx,
                                                 int* __restrict__ cnt,
                                                 int* __restrict__ srclist) {
  int e = blockIdx.x * 256 + threadIdx.x;
  if (e >= N_EDGES) return;
  int dst = ei[N_EDGES + e];
  int ni = nidx[dst];
  if (!ni) return;
  ni--;
  int pos = atomicAdd(&cnt[ni], 1);
  if (pos < 64) srclist[ni * 64 + pos] = ei[e];
}

// ---------------- per-dst aggregation: 4 dsts/wave, quarter-wave per dst -------
// Lane li (0..15) of quad q owns cols li*8..+7 (one uint4 row segment, head
// hh=li>>2). Per edge: 2 LDS reads + 1 uint4 gather + 8 FMA, no cross-lane
// epilogue (each lane owns its cols outright). 4 quads x unroll4 = 16 gathers
// in flight per wave (2x R9).
__global__ __launch_bounds__(256) void k_agg(const float* __restrict__ a_s,
                                             const float* __restrict__ a_d,
                                             const unsigned short* __restrict__ Wx,
                                             const int* __restrict__ nlist,
                                             const int* __restrict__ nw_cnt,
                                             const int* __restrict__ cnt,
                                             const int* __restrict__ srclist,
                                             const int* __restrict__ ei,
                                             const float* __restrict__ bias,
                                             unsigned short* __restrict__ hout) {
  __shared__ int sS[16][64];         // [wavequad][slot]
  __shared__ float sW[16][64 * 4];   // [wavequad][slot*4+head]
  int w = threadIdx.x >> 6, lane = threadIdx.x & 63;
  int q = lane >> 4, li = lane & 15;
  int wq = w * 4 + q;
  int wid = (blockIdx.x * 4 + w) * 4 + q;
  bool act = wid < nw_cnt[0];
  int dst = 0, degRaw = 0, deg = 0;
  float4 ad4 = {0.f, 0.f, 0.f, 0.f};
  float4 dsum = {0.f, 0.f, 0.f, 0.f};
  if (act) {
    dst = nlist[wid];
    degRaw = cnt[wid];
    deg = degRaw < 64 ? degRaw : 64;
    ad4 = *(const float4*)(a_d + (size_t)dst * 4);
    for (int t = li; t < deg; t += 16) {
      int sv = srclist[wid * 64 + t];
      float4 as = *(const float4*)(a_s + (size_t)sv * 4);
      float e0 = as.x + ad4.x; e0 = e0 > 0.f ? e0 : 0.2f * e0;
      float e1 = as.y + ad4.y; e1 = e1 > 0.f ? e1 : 0.2f * e1;
      float e2 = as.z + ad4.z; e2 = e2 > 0.f ? e2 : 0.2f * e2;
      float e3 = as.w + ad4.w; e3 = e3 > 0.f ? e3 : 0.2f * e3;
      float4 w4;
      w4.x = __expf(e0); w4.y = __expf(e1);
      w4.z = __expf(e2); w4.w = __expf(e3);
      sS[wq][t] = sv;
      *(float4*)(&sW[wq][t * 4]) = w4;
      dsum.x += w4.x; dsum.y += w4.y; dsum.z += w4.z; dsum.w += w4.w;
    }
  }
  __syncthreads();
  if (!act) return;

  // butterfly within quad (xor offsets < 16 stay inside the quad)
#pragma unroll
  for (int o = 8; o >= 1; o >>= 1) {
    dsum.x += __shfl_xor(dsum.x, o);
    dsum.y += __shfl_xor(dsum.y, o);
    dsum.z += __shfl_xor(dsum.z, o);
    dsum.w += __shfl_xor(dsum.w, o);
  }

  int hh = li >> 2;
  float4 as4 = *(const float4*)(a_s + (size_t)dst * 4);
  float s0 = as4.x + ad4.x; s0 = s0 > 0.f ? s0 : 0.2f * s0;
  float s1 = as4.y + ad4.y; s1 = s1 > 0.f ? s1 : 0.2f * s1;
  float s2 = as4.z + ad4.z; s2 = s2 > 0.f ? s2 : 0.2f * s2;
  float s3 = as4.w + ad4.w; s3 = s3 > 0.f ? s3 : 0.2f * s3;
  float w0 = __expf(s0), w1 = __expf(s1), w2 = __expf(s2), w3 = __expf(s3);
  float wSelf = hh < 2 ? (hh == 0 ? w0 : w1) : (hh == 2 ? w2 : w3);
  float denE = hh < 2 ? (hh == 0 ? dsum.x : dsum.y) : (hh == 2 ? dsum.z : dsum.w);
  float den = denE + wSelf;

  float acc[8];
  {
    uint4 u = *(const uint4*)(Wx + (size_t)dst * 128 + li * 8);
    acc[0] = wSelf * bs2f(u.x); acc[1] = wSelf * bs2f(u.x >> 16);
    acc[2] = wSelf * bs2f(u.y); acc[3] = wSelf * bs2f(u.y >> 16);
    acc[4] = wSelf * bs2f(u.z); acc[5] = wSelf * bs2f(u.z >> 16);
    acc[6] = wSelf * bs2f(u.w); acc[7] = wSelf * bs2f(u.w >> 16);
  }

  if (degRaw > 64) {
    // ---- correctness-only fallback (P ~ 1e-20): serial full-edge rescan ----
    float adH = hh < 2 ? (hh == 0 ? ad4.x : ad4.y) : (hh == 2 ? ad4.z : ad4.w);
    den = wSelf;
    for (int e = 0; e < N_EDGES; ++e) {
      if (ei[N_EDGES + e] == dst) {
        int sv = ei[e];
        float ash = a_s[(size_t)sv * 4 + hh];
        float ee = ash + adH; ee = ee > 0.f ? ee : 0.2f * ee;
        float wA = __expf(ee);
        den += wA;
        uint4 u = *(const uint4*)(Wx + (size_t)sv * 128 + li * 8);
        acc[0] += wA * bs2f(u.x); acc[1] += wA * bs2f(u.x >> 16);
        acc[2] += wA * bs2f(u.y); acc[3] += wA * bs2f(u.y >> 16);
        acc[4] += wA * bs2f(u.z); acc[5] += wA * bs2f(u.z >> 16);
        acc[6] += wA * bs2f(u.w); acc[7] += wA * bs2f(u.w >> 16);
      }
    }
    // note: acc was seeded with wSelf*row above; den rebuilt from scratch
  } else {
#pragma unroll 4
    for (int j = 0; j < deg; ++j) {
      int s = sS[wq][j];
      float wA = sW[wq][j * 4 + hh];
      uint4 u = *(const uint4*)(Wx + (size_t)s * 128 + li * 8);
      acc[0] += wA * bs2f(u.x); acc[1] += wA * bs2f(u.x >> 16);
      acc[2] += wA * bs2f(u.y); acc[3] += wA * bs2f(u.y >> 16);
      acc[4] += wA * bs2f(u.z); acc[5] += wA * bs2f(u.z >> 16);
      acc[6] += wA * bs2f(u.w); acc[7] += wA * bs2f(u.w >> 16);
    }
  }

  float inv = 1.0f / den;
  float4 b0 = *(const float4*)(bias + li * 8);
  float4 b1 = *(const float4*)(bias + li * 8 + 4);
  uint4 o;
  o.x = (unsigned int)f2bs(acc[0] * inv + b0.x)
      | ((unsigned int)f2bs(acc[1] * inv + b0.y) << 16);
  o.y = (unsigned int)f2bs(acc[2] * inv + b0.z)
      | ((unsigned int)f2bs(acc[3] * inv + b0.w) << 16);
  o.z = (unsigned int)f2bs(acc[4] * inv + b1.x)
      | ((unsigned int)f2bs(acc[5] * inv + b1.y) << 16);
  o.w = (unsigned int)f2bs(acc[6] * inv + b1.z)
      | ((unsigned int)f2bs(acc[7] * inv + b1.w) << 16);
  *(uint4*)(hout + (size_t)dst * 128 + li * 8) = o;
}

// ---------------- fused: msg = message @ fc_w^T + fc_b, then scoring ----------
__global__ __launch_bounds__(256) void k_msgscore(const float* __restrict__ message,
                                                  const float* __restrict__ fc_w,
                                                  const float* __restrict__ fc_b,
                                                  const unsigned short* __restrict__ h,
                                                  const int* __restrict__ indices,
                                                  float* __restrict__ out) {
  __shared__ float Sm[16][256];
  float* red = &Sm[0][0];
  int tid = threadIdx.x;
  int b0 = blockIdx.x * 16;
  for (int i = tid; i < 16 * 256; i += 256)
    Sm[i >> 8][i & 255] = message[(size_t)b0 * 256 + i];
  __syncthreads();
  int e = tid & 127, half = tid >> 7;
  float acc[16];
#pragma unroll
  for (int r = 0; r < 16; ++r) acc[r] = 0.f;
  const float* wrow = fc_w + (size_t)e * 256 + half * 128;
  for (int k = 0; k < 128; k += 4) {
    float4 w4 = *(const float4*)(wrow + k);
#pragma unroll
    for (int r = 0; r < 16; ++r) {
      float4 m4 = *(const float4*)(&Sm[r][half * 128 + k]);
      acc[r] += m4.x * w4.x + m4.y * w4.y + m4.z * w4.z + m4.w * w4.w;
    }
  }
  __syncthreads();
  if (half == 0) {
#pragma unroll
    for (int r = 0; r < 16; ++r) red[r * 128 + e] = acc[r];
  }
  __syncthreads();
  if (half == 1) {
#pragma unroll
    for (int r = 0; r < 16; ++r) red[r * 128 + e] += acc[r];
  }
  __syncthreads();
  for (int i = tid; i < 2048; i += 256) red[i] += fc_b[i & 127];
  __syncthreads();

  int r = tid >> 4, c = tid & 15;
  int idx = indices[(b0 + r) * 16 + c];
  const unsigned short* hr = h + (size_t)idx * 128;
  const float* mr = red + r * 128;
  float dot = 0.f;
#pragma unroll
  for (int k = 0; k < 128; k += 8) {
    uint4 qv = *(const uint4*)(hr + k);
    float4 m0 = *(const float4*)(mr + k);
    float4 m1 = *(const float4*)(mr + k + 4);
    dot += bs2f(qv.x) * m0.x + bs2f(qv.x >> 16) * m0.y
         + bs2f(qv.y) * m0.z + bs2f(qv.y >> 16) * m0.w
         + bs2f(qv.z) * m1.x + bs2f(qv.z >> 16) * m1.y
         + bs2f(qv.w) * m1.z + bs2f(qv.w >> 16) * m1.w;
  }
  float mx = dot;
#pragma unroll
  for (int o = 1; o < 16; o <<= 1) mx = fmaxf(mx, __shfl_xor(mx, o));
  float ex = __expf(dot - mx);
  float sum = ex;
#pragma unroll
  for (int o = 1; o < 16; o <<= 1) sum += __shfl_xor(sum, o);
  float lse = mx + __logf(sum);
  out[(b0 + r) * 16 + c] = dot - lse;
}

extern "C" void kernel_launch(void* const* d_in, const int* in_sizes, int n_in,
                              void* d_out, int out_size, void* d_ws, size_t ws_size,
                              hipStream_t stream) {
  (void)in_sizes; (void)n_in; (void)out_size; (void)ws_size;
  const float* message = (const float*)d_in[0];
  const float* x       = (const float*)d_in[1];
  const int*   ei      = (const int*)d_in[2];
  const int*   indices = (const int*)d_in[3];
  const float* W       = (const float*)d_in[4];
  const float* att_src = (const float*)d_in[5];
  const float* att_dst = (const float*)d_in[6];
  const float* bias    = (const float*)d_in[7];
  const float* fc_w    = (const float*)d_in[8];
  const float* fc_b    = (const float*)d_in[9];
  float* out = (float*)d_out;

  char* p = (char*)d_ws;
  auto alloc = [&](size_t bytes) -> char* {
    char* r = p;
    p += (bytes + 255) & ~(size_t)255;
    return r;
  };
  unsigned short* Wx = (unsigned short*)alloc((size_t)N_NODES * 128 * 2);
  unsigned short* h  = (unsigned short*)alloc((size_t)N_NODES * 128 * 2);
  float* a_s = (float*)alloc((size_t)N_NODES * 4 * 4);
  float* a_d = (float*)alloc((size_t)N_NODES * 4 * 4);
  unsigned short* Wtp = (unsigned short*)alloc((size_t)WTROWS * STR * 2);
  // ---- zeroed region: mark .. nw_cnt (one memset) ----
  int* mark      = (int*)alloc((size_t)N_NODES * 4);
  int* nidx      = (int*)alloc((size_t)N_NODES * 4);
  int* cnt       = (int*)alloc((size_t)MAXNEED * 4);
  int* nw_cnt    = (int*)alloc(4);
  // ---- end zeroed region ----
  int* nlist     = (int*)alloc((size_t)MAXNEED * 4);
  int* srclist   = (int*)alloc((size_t)MAXNEED * 64 * 4);

  hipMemsetAsync(mark, 0, (size_t)((char*)nlist - (char*)mark), stream);

  k_prep<<<128, 256, 0, stream>>>(W, att_src, att_dst, Wtp, indices, mark, nidx, nlist, nw_cnt);
  k_wx<<<WXBLOCKS, 256, 0, stream>>>(x, Wtp, Wx, a_s, a_d);
  k_scatter<<<N_EDGES / 256, 256, 0, stream>>>(ei, nidx, cnt, srclist);
  k_agg<<<MAXNEED / 16, 256, 0, stream>>>(a_s, a_d, Wx, nlist, nw_cnt, cnt, srclist, ei, bias, h);
  k_msgscore<<<BATCH / 16, 256, 0, stream>>>(message, fc_w, fc_b, h, indices, out);
}

// Round 11
// 192.689 us; speedup vs baseline: 2.6391x; 1.0072x over previous
//
#include <hip/hip_runtime.h>
#include <stdint.h>
#include <stddef.h>

#define N_NODES 100000
#define N_EDGES 1600000
#define F_IN 128
#define EMB 128
#define HEADS 4
#define D_HEAD 32
#define HIDDEN 256
#define BATCH 2048
#define CANDS 16
#define MAXNEED 32768 /* BATCH*CANDS upper bound on unique needed dsts */
#define WXBLOCKS 391  /* ceil(N_NODES/256); 4 chunks of 64 rows per block */
#define WTROWS 144    /* 128 W cols + 8 att-projection rows + 8 zero pad */
#define STR 136       /* padded row stride (shorts) */

typedef __attribute__((ext_vector_type(8))) short v8s;
typedef __attribute__((ext_vector_type(4))) float v4f;

__device__ __forceinline__ unsigned short f2bs(float f) {
  unsigned int u = __builtin_bit_cast(unsigned int, f);
  u = (u + 0x7fffu + ((u >> 16) & 1u)) >> 16;
  return (unsigned short)u;
}
__device__ __forceinline__ float bs2f(unsigned int s) {
  unsigned int u = (s & 0xffffu) << 16;
  return __builtin_bit_cast(float, u);
}

// ------- prep: padded Wt^T (+att-projection rows) + dedup-compact needed ------
__global__ __launch_bounds__(256) void k_prep(const float* __restrict__ W,
                                              const float* __restrict__ att_src,
                                              const float* __restrict__ att_dst,
                                              unsigned short* __restrict__ Wtp,
                                              const int* __restrict__ idx,
                                              int* __restrict__ mark,
                                              int* __restrict__ nidx,
                                              int* __restrict__ nlist,
                                              int* __restrict__ nw_cnt) {
  int i = blockIdx.x * 256 + threadIdx.x;
  if (i < 128 * STR) {
    int r = i / STR, c = i - r * STR;
    Wtp[i] = (c < 128) ? f2bs(W[c * 128 + r]) : (unsigned short)0;
  } else if (i < WTROWS * STR) {
    int ii = i - 128 * STR;
    int r = ii / STR, c = ii - r * STR;  // r: 0..15
    unsigned short v = 0;
    if (c < 128 && r < 8) {
      const float* att = (r < 4) ? att_src : att_dst;
      int hh = r & 3;
      float s = 0.f;
#pragma unroll
      for (int d = 0; d < 32; ++d) s += W[c * 128 + hh * 32 + d] * att[hh * 32 + d];
      v = f2bs(s);
    }
    Wtp[i] = v;
  }
  if (i < BATCH * CANDS) {
    int v = idx[i];
    if (atomicAdd(&mark[v], 1) == 0) {
      int p = atomicAdd(nw_cnt, 1);  // per-thread atomic: wave-coalesced (G12)
      nidx[v] = p + 1;
      nlist[p] = v;
    }
  }
}

// ---------------- Wx = x @ W (MFMA), Wt staged in LDS once per 256 rows --------
__global__ __launch_bounds__(256) void k_wx(const float* __restrict__ x,
                                            const unsigned short* __restrict__ Wtp,
                                            unsigned short* __restrict__ Wx,
                                            float* __restrict__ a_s,
                                            float* __restrict__ a_d) {
  __shared__ unsigned short wt[WTROWS * STR];  // 39168 B
  __shared__ unsigned short xs[64 * STR];      // 17408 B
  int tid = threadIdx.x;

  {
    const uint4* s = (const uint4*)Wtp;
    uint4* d = (uint4*)wt;
#pragma unroll
    for (int it = 0; it < 10; ++it) {
      int i = it * 256 + tid;
      if (i < WTROWS * STR / 8) d[i] = s[i];
    }
  }

  int w = tid >> 6, lane = tid & 63;
  int m = lane & 15, quad = lane >> 4;

  for (int chunk = 0; chunk < 4; ++chunk) {
    int rbase = blockIdx.x * 256 + chunk * 64;

    float4 f[8];
#pragma unroll
    for (int it = 0; it < 4; ++it) {
      int cid = it * 256 + tid;
      int row = cid >> 4, c = cid & 15;
      int gr = rbase + row;
      if (gr >= N_NODES) gr = N_NODES - 1;
      const float4* gp = (const float4*)(x + (size_t)gr * 128 + c * 8);
      f[2 * it] = gp[0];
      f[2 * it + 1] = gp[1];
    }
#pragma unroll
    for (int it = 0; it < 4; ++it) {
      int cid = it * 256 + tid;
      int row = cid >> 4, c = cid & 15;
      float4 f0 = f[2 * it], f1 = f[2 * it + 1];
      v8s a;
      a[0] = (short)f2bs(f0.x); a[1] = (short)f2bs(f0.y);
      a[2] = (short)f2bs(f0.z); a[3] = (short)f2bs(f0.w);
      a[4] = (short)f2bs(f1.x); a[5] = (short)f2bs(f1.y);
      a[6] = (short)f2bs(f1.z); a[7] = (short)f2bs(f1.w);
      *(v8s*)(&xs[row * STR + c * 8]) = a;
    }
    __syncthreads();

    v8s afrag[4];
#pragma unroll
    for (int t = 0; t < 4; ++t)
      afrag[t] = *(const v8s*)(&xs[(w * 16 + m) * STR + t * 32 + quad * 8]);

    v4f acc[9];
#pragma unroll
    for (int nt = 0; nt < 9; ++nt) {
      v4f a0 = {0.f, 0.f, 0.f, 0.f};
      const unsigned short* brow = wt + (size_t)(nt * 16 + m) * STR;
#pragma unroll
      for (int t = 0; t < 4; ++t) {
        v8s b = *(const v8s*)(brow + t * 32 + quad * 8);
        a0 = __builtin_amdgcn_mfma_f32_16x16x32_bf16(afrag[t], b, a0, 0, 0, 0);
      }
      acc[nt] = a0;
    }

#pragma unroll
    for (int r = 0; r < 4; ++r) {
      int orow = rbase + w * 16 + quad * 4 + r;
      if (orow < N_NODES) {
        if (m < 4) a_s[(size_t)orow * 4 + m] = acc[8][r];
        else if (m < 8) a_d[(size_t)orow * 4 + m - 4] = acc[8][r];
      }
    }

    __syncthreads();
#pragma unroll
    for (int nt = 0; nt < 8; ++nt)
#pragma unroll
      for (int r = 0; r < 4; ++r)
        xs[(w * 16 + quad * 4 + r) * STR + nt * 16 + m] = f2bs(acc[nt][r]);
    asm volatile("s_waitcnt lgkmcnt(0)" ::: "memory");
#pragma unroll
    for (int j = 0; j < 4; ++j) {
      int fr = 4 * j + (lane >> 4);
      int fc = (lane & 15) * 8;
      int grow = rbase + w * 16 + fr;
      v8s v = *(const v8s*)(&xs[(w * 16 + fr) * STR + fc]);
      if (grow < N_NODES) *(v8s*)(&Wx[(size_t)grow * 128 + fc]) = v;
    }
    __syncthreads();
  }
}

// ---------------- scatter srcs into fixed 64-slot buckets ----------------------
__global__ __launch_bounds__(256) void k_scatter(const int* __restrict__ ei,
                                                 const int* __restrict__ nidx,
                                                 int* __restrict__ cnt,
                                                 int* __restrict__ srclist) {
  int e = blockIdx.x * 256 + threadIdx.x;
  if (e >= N_EDGES) return;
  int dst = ei[N_EDGES + e];
  int ni = nidx[dst];
  if (!ni) return;
  ni--;
  int pos = atomicAdd(&cnt[ni], 1);
  if (pos < 64) srclist[ni * 64 + pos] = ei[e];
}

// ---------------- per-dst aggregation: 4 dsts/wave, quarter-wave per dst -------
__global__ __launch_bounds__(256) void k_agg(const float* __restrict__ a_s,
                                             const float* __restrict__ a_d,
                                             const unsigned short* __restrict__ Wx,
                                             const int* __restrict__ nlist,
                                             const int* __restrict__ nw_cnt,
                                             const int* __restrict__ cnt,
                                             const int* __restrict__ srclist,
                                             const int* __restrict__ ei,
                                             const float* __restrict__ bias,
                                             unsigned short* __restrict__ hout) {
  __shared__ int sS[16][64];
  __shared__ float sW[16][64 * 4];
  int w = threadIdx.x >> 6, lane = threadIdx.x & 63;
  int q = lane >> 4, li = lane & 15;
  int wq = w * 4 + q;
  int wid = (blockIdx.x * 4 + w) * 4 + q;
  bool act = wid < nw_cnt[0];
  int dst = 0, degRaw = 0, deg = 0;
  float4 ad4 = {0.f, 0.f, 0.f, 0.f};
  float4 dsum = {0.f, 0.f, 0.f, 0.f};
  if (act) {
    dst = nlist[wid];
    degRaw = cnt[wid];
    deg = degRaw < 64 ? degRaw : 64;
    ad4 = *(const float4*)(a_d + (size_t)dst * 4);
    for (int t = li; t < deg; t += 16) {
      int sv = srclist[wid * 64 + t];
      float4 as = *(const float4*)(a_s + (size_t)sv * 4);
      float e0 = as.x + ad4.x; e0 = e0 > 0.f ? e0 : 0.2f * e0;
      float e1 = as.y + ad4.y; e1 = e1 > 0.f ? e1 : 0.2f * e1;
      float e2 = as.z + ad4.z; e2 = e2 > 0.f ? e2 : 0.2f * e2;
      float e3 = as.w + ad4.w; e3 = e3 > 0.f ? e3 : 0.2f * e3;
      float4 w4;
      w4.x = __expf(e0); w4.y = __expf(e1);
      w4.z = __expf(e2); w4.w = __expf(e3);
      sS[wq][t] = sv;
      *(float4*)(&sW[wq][t * 4]) = w4;
      dsum.x += w4.x; dsum.y += w4.y; dsum.z += w4.z; dsum.w += w4.w;
    }
  }
  __syncthreads();
  if (!act) return;

#pragma unroll
  for (int o = 8; o >= 1; o >>= 1) {
    dsum.x += __shfl_xor(dsum.x, o);
    dsum.y += __shfl_xor(dsum.y, o);
    dsum.z += __shfl_xor(dsum.z, o);
    dsum.w += __shfl_xor(dsum.w, o);
  }

  int hh = li >> 2;
  float4 as4 = *(const float4*)(a_s + (size_t)dst * 4);
  float s0 = as4.x + ad4.x; s0 = s0 > 0.f ? s0 : 0.2f * s0;
  float s1 = as4.y + ad4.y; s1 = s1 > 0.f ? s1 : 0.2f * s1;
  float s2 = as4.z + ad4.z; s2 = s2 > 0.f ? s2 : 0.2f * s2;
  float s3 = as4.w + ad4.w; s3 = s3 > 0.f ? s3 : 0.2f * s3;
  float w0 = __expf(s0), w1 = __expf(s1), w2 = __expf(s2), w3 = __expf(s3);
  float wSelf = hh < 2 ? (hh == 0 ? w0 : w1) : (hh == 2 ? w2 : w3);
  float denE = hh < 2 ? (hh == 0 ? dsum.x : dsum.y) : (hh == 2 ? dsum.z : dsum.w);
  float den = denE + wSelf;

  float acc[8];
  {
    uint4 u = *(const uint4*)(Wx + (size_t)dst * 128 + li * 8);
    acc[0] = wSelf * bs2f(u.x); acc[1] = wSelf * bs2f(u.x >> 16);
    acc[2] = wSelf * bs2f(u.y); acc[3] = wSelf * bs2f(u.y >> 16);
    acc[4] = wSelf * bs2f(u.z); acc[5] = wSelf * bs2f(u.z >> 16);
    acc[6] = wSelf * bs2f(u.w); acc[7] = wSelf * bs2f(u.w >> 16);
  }

  if (degRaw > 64) {
    // correctness-only fallback (P ~ 1e-20): serial full-edge rescan
    float adH = hh < 2 ? (hh == 0 ? ad4.x : ad4.y) : (hh == 2 ? ad4.z : ad4.w);
    den = wSelf;
    for (int e = 0; e < N_EDGES; ++e) {
      if (ei[N_EDGES + e] == dst) {
        int sv = ei[e];
        float ash = a_s[(size_t)sv * 4 + hh];
        float ee = ash + adH; ee = ee > 0.f ? ee : 0.2f * ee;
        float wA = __expf(ee);
        den += wA;
        uint4 u = *(const uint4*)(Wx + (size_t)sv * 128 + li * 8);
        acc[0] += wA * bs2f(u.x); acc[1] += wA * bs2f(u.x >> 16);
        acc[2] += wA * bs2f(u.y); acc[3] += wA * bs2f(u.y >> 16);
        acc[4] += wA * bs2f(u.z); acc[5] += wA * bs2f(u.z >> 16);
        acc[6] += wA * bs2f(u.w); acc[7] += wA * bs2f(u.w >> 16);
      }
    }
  } else {
#pragma unroll 4
    for (int j = 0; j < deg; ++j) {
      int s = sS[wq][j];
      float wA = sW[wq][j * 4 + hh];
      uint4 u = *(const uint4*)(Wx + (size_t)s * 128 + li * 8);
      acc[0] += wA * bs2f(u.x); acc[1] += wA * bs2f(u.x >> 16);
      acc[2] += wA * bs2f(u.y); acc[3] += wA * bs2f(u.y >> 16);
      acc[4] += wA * bs2f(u.z); acc[5] += wA * bs2f(u.z >> 16);
      acc[6] += wA * bs2f(u.w); acc[7] += wA * bs2f(u.w >> 16);
    }
  }

  float inv = 1.0f / den;
  float4 b0 = *(const float4*)(bias + li * 8);
  float4 b1 = *(const float4*)(bias + li * 8 + 4);
  uint4 o;
  o.x = (unsigned int)f2bs(acc[0] * inv + b0.x)
      | ((unsigned int)f2bs(acc[1] * inv + b0.y) << 16);
  o.y = (unsigned int)f2bs(acc[2] * inv + b0.z)
      | ((unsigned int)f2bs(acc[3] * inv + b0.w) << 16);
  o.z = (unsigned int)f2bs(acc[4] * inv + b1.x)
      | ((unsigned int)f2bs(acc[5] * inv + b1.y) << 16);
  o.w = (unsigned int)f2bs(acc[6] * inv + b1.z)
      | ((unsigned int)f2bs(acc[7] * inv + b1.w) << 16);
  *(uint4*)(hout + (size_t)dst * 128 + li * 8) = o;
}

// ------- fused msg GEMM + scoring: 8 rows/block (256 blocks, 2x R10 TLP) ------
__global__ __launch_bounds__(256) void k_msgscore(const float* __restrict__ message,
                                                  const float* __restrict__ fc_w,
                                                  const float* __restrict__ fc_b,
                                                  const unsigned short* __restrict__ h,
                                                  const int* __restrict__ indices,
                                                  float* __restrict__ out) {
  __shared__ float Sm[8][256];   // 8 KB message tile
  __shared__ float red[8 * 128]; // 4 KB msg result
  __shared__ float sp[128];      // scoring partials
  int tid = threadIdx.x;
  int b0 = blockIdx.x * 8;
  for (int i = tid; i < 8 * 256; i += 256)
    Sm[i >> 8][i & 255] = message[(size_t)b0 * 256 + i];
  __syncthreads();
  int e = tid & 127, half = tid >> 7;
  float acc[8];
#pragma unroll
  for (int r = 0; r < 8; ++r) acc[r] = 0.f;
  const float* wrow = fc_w + (size_t)e * 256 + half * 128;
  for (int k = 0; k < 128; k += 4) {
    float4 w4 = *(const float4*)(wrow + k);
#pragma unroll
    for (int r = 0; r < 8; ++r) {
      float4 m4 = *(const float4*)(&Sm[r][half * 128 + k]);
      acc[r] += m4.x * w4.x + m4.y * w4.y + m4.z * w4.z + m4.w * w4.w;
    }
  }
  __syncthreads();
  if (half == 0) {
#pragma unroll
    for (int r = 0; r < 8; ++r) red[r * 128 + e] = acc[r];
  }
  __syncthreads();
  if (half == 1) {
#pragma unroll
    for (int r = 0; r < 8; ++r) red[r * 128 + e] += acc[r];
  }
  __syncthreads();
  for (int i = tid; i < 1024; i += 256) red[i] += fc_b[i & 127];
  __syncthreads();

  // scoring: 128 dots (8 rows x 16 cands), 2 threads per dot (half-split k)
  int r = (tid & 127) >> 4, c = tid & 15;
  int idx = indices[(b0 + r) * 16 + c];
  const unsigned short* hr = h + (size_t)idx * 128 + half * 64;
  const float* mr = red + r * 128 + half * 64;
  float dot = 0.f;
#pragma unroll
  for (int k = 0; k < 64; k += 8) {
    uint4 qv = *(const uint4*)(hr + k);
    float4 m0 = *(const float4*)(mr + k);
    float4 m1 = *(const float4*)(mr + k + 4);
    dot += bs2f(qv.x) * m0.x + bs2f(qv.x >> 16) * m0.y
         + bs2f(qv.y) * m0.z + bs2f(qv.y >> 16) * m0.w
         + bs2f(qv.z) * m1.x + bs2f(qv.z >> 16) * m1.y
         + bs2f(qv.w) * m1.z + bs2f(qv.w >> 16) * m1.w;
  }
  if (half == 1) sp[tid - 128] = dot;
  __syncthreads();
  if (half == 0) {
    dot += sp[tid];
    float mx = dot;
#pragma unroll
    for (int o = 1; o < 16; o <<= 1) mx = fmaxf(mx, __shfl_xor(mx, o));
    float ex = __expf(dot - mx);
    float sum = ex;
#pragma unroll
    for (int o = 1; o < 16; o <<= 1) sum += __shfl_xor(sum, o);
    float lse = mx + __logf(sum);
    out[(b0 + r) * 16 + c] = dot - lse;
  }
}

extern "C" void kernel_launch(void* const* d_in, const int* in_sizes, int n_in,
                              void* d_out, int out_size, void* d_ws, size_t ws_size,
                              hipStream_t stream) {
  (void)in_sizes; (void)n_in; (void)out_size; (void)ws_size;
  const float* message = (const float*)d_in[0];
  const float* x       = (const float*)d_in[1];
  const int*   ei      = (const int*)d_in[2];
  const int*   indices = (const int*)d_in[3];
  const float* W       = (const float*)d_in[4];
  const float* att_src = (const float*)d_in[5];
  const float* att_dst = (const float*)d_in[6];
  const float* bias    = (const float*)d_in[7];
  const float* fc_w    = (const float*)d_in[8];
  const float* fc_b    = (const float*)d_in[9];
  float* out = (float*)d_out;

  char* p = (char*)d_ws;
  auto alloc = [&](size_t bytes) -> char* {
    char* r = p;
    p += (bytes + 255) & ~(size_t)255;
    return r;
  };
  unsigned short* Wx = (unsigned short*)alloc((size_t)N_NODES * 128 * 2);
  unsigned short* h  = (unsigned short*)alloc((size_t)N_NODES * 128 * 2);
  float* a_s = (float*)alloc((size_t)N_NODES * 4 * 4);
  float* a_d = (float*)alloc((size_t)N_NODES * 4 * 4);
  unsigned short* Wtp = (unsigned short*)alloc((size_t)WTROWS * STR * 2);
  // ---- zeroed region: mark .. nw_cnt (one memset) ----
  int* mark      = (int*)alloc((size_t)N_NODES * 4);
  int* nidx      = (int*)alloc((size_t)N_NODES * 4);
  int* cnt       = (int*)alloc((size_t)MAXNEED * 4);
  int* nw_cnt    = (int*)alloc(4);
  // ---- end zeroed region ----
  int* nlist     = (int*)alloc((size_t)MAXNEED * 4);
  int* srclist   = (int*)alloc((size_t)MAXNEED * 64 * 4);

  hipMemsetAsync(mark, 0, (size_t)((char*)nlist - (char*)mark), stream);

  k_prep<<<128, 256, 0, stream>>>(W, att_src, att_dst, Wtp, indices, mark, nidx, nlist, nw_cnt);
  k_wx<<<WXBLOCKS, 256, 0, stream>>>(x, Wtp, Wx, a_s, a_d);
  k_scatter<<<N_EDGES / 256, 256, 0, stream>>>(ei, nidx, cnt, srclist);
  k_agg<<<MAXNEED / 16, 256, 0, stream>>>(a_s, a_d, Wx, nlist, nw_cnt, cnt, srclist, ei, bias, h);
  k_msgscore<<<BATCH / 8, 256, 0, stream>>>(message, fc_w, fc_b, h, indices, out);
}